// Round 8
// baseline (227.343 us; speedup 1.0000x reference)
//
#include <hip/hip_runtime.h>
#include <hip/hip_bf16.h>

#define NNODES 100000
#define NEDGES 1600000
#define INC 128
#define HIDC 64
#define BSHIFT 7                      // 128 nodes per bucket
#define NB ((NNODES + 127) / 128)     // 782 buckets
#define TILE 4096                     // edges per fill1 workgroup (16/thread)
#define HSLOTS 4096                   // LDS hash slots in fill2 (16 KB)
#define CAP 4096                      // staging words per bucket (avg load ~2046)
#define CAPE 4096                     // csr words per bucket (rows padded to x8)
#define NBLK_FILL ((NEDGES + TILE - 1) / TILE)   // 391
#define NBLK_LIN ((NNODES + 127) / 128)          // 782 (128 nodes per GEMM block)

typedef short bf16x8 __attribute__((ext_vector_type(8)));
typedef float f32x4 __attribute__((ext_vector_type(4)));

__device__ __forceinline__ float bf2f(unsigned short h) {
    return __uint_as_float((unsigned)h << 16);
}
__device__ __forceinline__ unsigned short f2bf(float f) {
    __hip_bfloat16 h = __float2bfloat16(f);
    return *(unsigned short*)&h;
}

// ---- prep kernel: w1 -> transposed bf16 hi/lo split; w44/bias4 fold; sentinel ----
__global__ __launch_bounds__(256) void prep_w_kernel(
        const float* __restrict__ w1, unsigned short* __restrict__ wTh,
        unsigned short* __restrict__ wTl,
        const float* __restrict__ w2_lin, const float* __restrict__ b2,
        const float* __restrict__ wc, float* __restrict__ w44,
        float* __restrict__ bias4, unsigned short* __restrict__ out) {
    int t = threadIdx.x;
    int e = blockIdx.x * 256 + t;            // 0..8191 over wT[64][128]
    int c = e >> 7, k = e & 127;
    float v = w1[k * 64 + c];
    unsigned short hi = f2bf(v);
    wTh[e] = hi;
    wTl[e] = f2bf(v - bf2f(hi));
    if (blockIdx.x == 0) {
        if (t < 16)   // zero sentinel row for padded gathers
            *(ushort4*)(out + (size_t)NNODES * 64 + t * 4) = make_ushort4(0, 0, 0, 0);
        int kk = t >> 2, j = t & 3;
        float a = 0.0f;
#pragma unroll 8
        for (int i = 0; i < 64; i++) {
            float w4 = (j < 2) ? wc[i * 2 + j] : wc[(64 + i) * 2 + (j - 2)];
            a += w2_lin[kk * 64 + i] * w4;
        }
        w44[kk * 4 + j] = a;
        if (kk == 0) {
            float bb4 = 0.0f;
            for (int i = 0; i < 64; i++) {
                float w4 = (j < 2) ? wc[i * 2 + j] : wc[(64 + i) * 2 + (j - 2)];
                bb4 += b2[i] * w4;
            }
            bias4[j] = bb4;
        }
    }
}

// ---- fat kernel: fill1 binning (blocks [0, NBLK_FILL)) + MFMA lin1 GEMM (rest) ----
// GEMM is bf16x3 error-compensated: x = xh+xl, w = wh+wl (bf16 each);
// h = xh*wh + xh*wl + xl*wh  (xl*wl term ~2^-18 rel, dropped).
// Hybrid staging (R6/R7): A direct global->reg (zero reuse), B LDS-staged
// (4x reuse). R8: 128 nodes/block, TWO 16-row tiles per wave -> half the
// serial block slots, each B ds_read feeds 6 MFMAs (was 3), 16 A-loads in
// flight (was 8). Per-block fixed latency (A round-trip + barrier) is paid
// half as often.
__global__ __launch_bounds__(256, 3) void fat_kernel(
        const float* __restrict__ x,
        const unsigned short* __restrict__ wTh, const unsigned short* __restrict__ wTl,
        const float* __restrict__ b, unsigned short* __restrict__ out,
        const int* __restrict__ src, const int* __restrict__ dst,
        int* __restrict__ bucket_fill, unsigned int* __restrict__ staging) {
    __shared__ alignas(16) unsigned char smem[32768];   // union: fill1 22.6KB | B 32KB
    int t = threadIdx.x;
    if (blockIdx.x < NBLK_FILL) {
        // ---------------- fill1 branch ----------------
        int* cnt = (int*)smem;
        int* basepos = cnt + NB;
        unsigned int* svl = (unsigned int*)(basepos + NB);   // 4096 words = TILE
        for (int i = t; i < NB; i += 256) cnt[i] = 0;
        __syncthreads();
        int tile0 = blockIdx.x * TILE;
        int meta[16];
#pragma unroll
        for (int i = 0; i < 16; i++) {
            int e = tile0 + i * 256 + t;
            meta[i] = -1;
            if (e < NEDGES) {
                int s = src[e], d = dst[e];
                int bkt = d >> BSHIFT;
                int r = atomicAdd(&cnt[bkt], 1);     // < TILE = 4096 (12 bits)
                meta[i] = (bkt << 12) | r;
                svl[i * 256 + t] = ((unsigned)(d & 127) << 17) | (unsigned)s;
            }
        }
        __syncthreads();
        for (int i = t; i < NB; i += 256) {
            int c = cnt[i];
            int g = (c > 0) ? atomicAdd(&bucket_fill[i], c) : 0;
            basepos[i] = (i << 12) + g;              // staging region = [i*CAP, ...)
        }
        __syncthreads();
#pragma unroll
        for (int i = 0; i < 16; i++) {
            if (meta[i] >= 0) {
                int bkt = meta[i] >> 12, r = meta[i] & 4095;
                staging[basepos[bkt] + r] = svl[i * 256 + t];
            }
        }
    } else {
        // ----- hybrid MFMA GEMM branch: 128 nodes x 64 cols, K=128 -----
        unsigned short* s_bh = (unsigned short*)smem;        // [64][128] swizzled
        unsigned short* s_bl = s_bh + 64 * 128;
        int node0 = (blockIdx.x - NBLK_FILL) * 128;
        int l = t & 63, wv = t >> 6;
        int mr = l & 15, g = l >> 4;
        int r0 = wv * 16 + mr;
        int nodeA = node0 + r0;
        int nodeB = node0 + 64 + r0;
        bool vA = (nodeA < NNODES), vB = (nodeB < NNODES);
        const float* xrA = x + (size_t)nodeA * INC;
        const float* xrB = x + (size_t)nodeB * INC;
        // issue all 16 A loads up-front (independent -> in flight together)
        float4 vxA[8], vxB[8];
#pragma unroll
        for (int ks = 0; ks < 4; ks++) {
            int k0 = ks * 32 + g * 8;
            vxA[2 * ks]     = vA ? *(const float4*)(xrA + k0) : make_float4(0.f, 0.f, 0.f, 0.f);
            vxA[2 * ks + 1] = vA ? *(const float4*)(xrA + k0 + 4) : make_float4(0.f, 0.f, 0.f, 0.f);
            vxB[2 * ks]     = vB ? *(const float4*)(xrB + k0) : make_float4(0.f, 0.f, 0.f, 0.f);
            vxB[2 * ks + 1] = vB ? *(const float4*)(xrB + k0 + 4) : make_float4(0.f, 0.f, 0.f, 0.f);
        }
        // cooperative B staging: coalesced, swizzled store
#pragma unroll
        for (int i = 0; i < 4; i++) {
            int e = i * 256 + t;                     // ushort8 chunk of wT[64][128]
            uint4 vh = *(const uint4*)(wTh + (size_t)e * 8);
            uint4 vl = *(const uint4*)(wTl + (size_t)e * 8);
            int col = e >> 4, k0 = (e & 15) * 8;
            int ke = k0 ^ ((col & 7) << 3);
            *(uint4*)&s_bh[col * 128 + ke] = vh;
            *(uint4*)&s_bl[col * 128 + ke] = vl;
        }
        __syncthreads();
        f32x4 accA[4] = {{0.f, 0.f, 0.f, 0.f}, {0.f, 0.f, 0.f, 0.f},
                         {0.f, 0.f, 0.f, 0.f}, {0.f, 0.f, 0.f, 0.f}};
        f32x4 accB[4] = {{0.f, 0.f, 0.f, 0.f}, {0.f, 0.f, 0.f, 0.f},
                         {0.f, 0.f, 0.f, 0.f}, {0.f, 0.f, 0.f, 0.f}};
#pragma unroll
        for (int ks = 0; ks < 4; ks++) {
            int k0 = ks * 32 + g * 8;
            float xvA[8] = {vxA[2 * ks].x, vxA[2 * ks].y, vxA[2 * ks].z, vxA[2 * ks].w,
                            vxA[2 * ks + 1].x, vxA[2 * ks + 1].y,
                            vxA[2 * ks + 1].z, vxA[2 * ks + 1].w};
            float xvB[8] = {vxB[2 * ks].x, vxB[2 * ks].y, vxB[2 * ks].z, vxB[2 * ks].w,
                            vxB[2 * ks + 1].x, vxB[2 * ks + 1].y,
                            vxB[2 * ks + 1].z, vxB[2 * ks + 1].w};
            bf16x8 ahA, alA, ahB, alB;
#pragma unroll
            for (int j = 0; j < 8; j++) {
                unsigned short hA = f2bf(xvA[j]);
                ahA[j] = (short)hA;
                alA[j] = (short)f2bf(xvA[j] - bf2f(hA));
                unsigned short hB = f2bf(xvB[j]);
                ahB[j] = (short)hB;
                alB[j] = (short)f2bf(xvB[j] - bf2f(hB));
            }
#pragma unroll
            for (int cb = 0; cb < 4; cb++) {
                int col = cb * 16 + mr;
                int ko = k0 ^ ((col & 7) << 3);
                bf16x8 bh = *(const bf16x8*)&s_bh[col * 128 + ko];
                bf16x8 bl = *(const bf16x8*)&s_bl[col * 128 + ko];
                accA[cb] = __builtin_amdgcn_mfma_f32_16x16x32_bf16(ahA, bh, accA[cb], 0, 0, 0);
                accA[cb] = __builtin_amdgcn_mfma_f32_16x16x32_bf16(ahA, bl, accA[cb], 0, 0, 0);
                accA[cb] = __builtin_amdgcn_mfma_f32_16x16x32_bf16(alA, bh, accA[cb], 0, 0, 0);
                accB[cb] = __builtin_amdgcn_mfma_f32_16x16x32_bf16(ahB, bh, accB[cb], 0, 0, 0);
                accB[cb] = __builtin_amdgcn_mfma_f32_16x16x32_bf16(ahB, bl, accB[cb], 0, 0, 0);
                accB[cb] = __builtin_amdgcn_mfma_f32_16x16x32_bf16(alB, bh, accB[cb], 0, 0, 0);
            }
        }
#pragma unroll
        for (int cb = 0; cb < 4; cb++) {
            int col = cb * 16 + mr;
            float bb = b[col];
#pragma unroll
            for (int r = 0; r < 4; r++) {
                int nA = node0 + wv * 16 + g * 4 + r;
                if (nA < NNODES)
                    out[(size_t)nA * 64 + col] = f2bf(accA[cb][r] + bb);
                int nB = nA + 64;
                if (nB < NNODES)
                    out[(size_t)nB * 64 + col] = f2bf(accB[cb][r] + bb);
            }
        }
    }
}

// fill pass 2: one WG per 128-node bucket, fixed csr region [b*CAPE, ...).
// Rows padded to x8 with sentinel n_nodes (points at the zero row).
// csr_src stores BYTE offsets (s*128) of the 128-B bufA rows.
__global__ __launch_bounds__(256) void fill2_kernel(
        const int* __restrict__ bucket_fill, const unsigned int* __restrict__ staging,
        int* __restrict__ csr_src, int* __restrict__ row_start,
        int* __restrict__ row_pdeg, float* __restrict__ norm, int n_nodes) {
    __shared__ int cnt[128];
    __shared__ int dcount[128];
    __shared__ int off[128];
    __shared__ int pscan[128];
    __shared__ unsigned short rank16[CAP];   // 8 KB
    __shared__ unsigned int ht[HSLOTS];      // 16 KB
    int t = threadIdx.x;
    int b = blockIdx.x;
    int node0 = b << BSHIFT;
    int nn = min(128, n_nodes - node0);
    if (t < 128) { cnt[t] = 0; dcount[t] = 0; }
    {
        uint4* h4 = (uint4*)ht;
        uint4 ff = make_uint4(0xFFFFFFFFu, 0xFFFFFFFFu, 0xFFFFFFFFu, 0xFFFFFFFFu);
        for (int i = t; i < HSLOTS / 4; i += 256) h4[i] = ff;
    }
    __syncthreads();
    int start = b << 12;
    int total = bucket_fill[b];
    // phase A: count + rank + dedup
    for (int li = t; li < total; li += 256) {
        unsigned int w = staging[start + li];
        int s = (int)(w & 0x1FFFFu);
        int dl = (int)(w >> 17);
        int r = atomicAdd(&cnt[dl], 1);
        rank16[li] = (unsigned short)r;
        if (s != node0 + dl) {  // self-loops merge with the I-diagonal
            unsigned int slot = ((w * 2654435761u) >> 13) & (HSLOTS - 1);
            while (true) {
                unsigned int prev = atomicCAS(&ht[slot], 0xFFFFFFFFu, w);
                if (prev == 0xFFFFFFFFu) { atomicAdd(&dcount[dl], 1); break; }
                if (prev == w) break;
                slot = (slot + 1) & (HSLOTS - 1);
            }
        }
    }
    __syncthreads();
    // exclusive prefix of x8-padded counts -> csr offsets within [b*CAPE, ...)
    int cv = 0, pv = 0;
    if (t < 128) {
        cv = cnt[t];
        pv = (cv + 7) & ~7;
        pscan[t] = pv;
    }
    __syncthreads();
    for (int o = 1; o < 128; o <<= 1) {
        int xx = (t >= o && t < 128) ? pscan[t - o] : 0;
        __syncthreads();
        if (t < 128) pscan[t] += xx;
        __syncthreads();
    }
    if (t < 128) off[t] = b * CAPE + pscan[t] - pv;
    __syncthreads();
    if (t < nn) {
        row_start[node0 + t] = off[t];
        row_pdeg[node0 + t] = pv;
        norm[node0 + t] = 1.0f / (1.0f + (float)dcount[t]);
    }
    // sentinel-pad the tail of each row (byte offset of the zero row)
    if (t < 128)
        for (int k = cv; k < pv; k++) csr_src[off[t] + k] = n_nodes << 7;
    // phase B: scatter csr (byte offsets: s*128)
    for (int li = t; li < total; li += 256) {
        unsigned int w = staging[start + li];
        int s = (int)(w & 0x1FFFFu);
        int dl = (int)(w >> 17);
        csr_src[off[dl] + (int)rank16[li]] = s << 7;
    }
}

// Four nodes per wave: lanes 0-31 own nodes {4q, 4q+1}, lanes 32-63 own
// {4q+2, 4q+3}. Two independent edge streams (X=even node, Y=odd node) per
// half, each keeping the proven wd0/wd1 edge-pairing -> MLP=4 dword gathers
// in flight at the same ~4 VALU/edge. Each dword wave-load still fetches
// exactly 2 full 128-B h1 rows. 100000 = 4*25000: grid exact, no guards.
// csr holds pre-shifted byte offsets (1 v_add addressing); tail slots clamp
// to the sentinel zero row (L1-resident). Fused PAN combine + relu + rank-4
// projection -> u; h1 never hits global memory.
__global__ void agg_h_kernel(const unsigned int* __restrict__ lin32,
                             const int* __restrict__ row_start,
                             const int* __restrict__ row_pdeg,
                             const int* __restrict__ csr_src,
                             const float* __restrict__ norm,
                             const float* __restrict__ wpan, const float* __restrict__ w44,
                             const float* __restrict__ bias4, float* __restrict__ u,
                             int n_nodes) {
    int t = threadIdx.x;
    int lane = t & 63;
    int sl = lane & 31;                      // channel dword / edge slot
    int h5 = lane >> 5;                      // half: owns nodes 4q+2*h5 + {0,1}
    int quad = blockIdx.x * 4 + (t >> 6);
    if (blockIdx.x == 0 && t < 4) u[n_nodes * 4 + t] = 0.0f;  // zero row for agg_pq4 pads
    int nX = quad * 4 + h5 * 2;
    int nY = nX + 1;
    int e0X = row_start[nX], pdX = row_pdeg[nX];
    int e0Y = row_start[nY], pdY = row_pdeg[nY];
    int pm = max(pdX, pdY);
    int pmax = max(pm, __shfl_xor(pm, 32));  // wave-uniform chunk bound
    int sentB = n_nodes << 7;                // byte offset of the zero row
    unsigned sl4 = (unsigned)sl * 4;
    const char* base8 = (const char*)lin32;
    float xL0 = 0.f, xH0 = 0.f, xL1 = 0.f, xH1 = 0.f;
    float yL0 = 0.f, yH0 = 0.f, yL1 = 0.f, yH1 = 0.f;
    for (int base = 0; base < pmax; base += 32) {
        int li = base + sl;
        int soX = (li < pdX) ? csr_src[e0X + li] : sentB;
        int soY = (li < pdY) ? csr_src[e0Y + li] : sentB;
        int m = min(32, pmax - base);        // wave-uniform, multiple of 8
#pragma unroll
        for (int i = 0; i < 32; i += 2) {
            if (i < m) {
                int xA0 = __builtin_amdgcn_readlane(soX, i);
                int xB0 = __builtin_amdgcn_readlane(soX, 32 + i);
                int xA1 = __builtin_amdgcn_readlane(soX, i + 1);
                int xB1 = __builtin_amdgcn_readlane(soX, 33 + i);
                int yA0 = __builtin_amdgcn_readlane(soY, i);
                int yB0 = __builtin_amdgcn_readlane(soY, 32 + i);
                int yA1 = __builtin_amdgcn_readlane(soY, i + 1);
                int yB1 = __builtin_amdgcn_readlane(soY, 33 + i);
                int ox0 = h5 ? xB0 : xA0;
                int ox1 = h5 ? xB1 : xA1;
                int oy0 = h5 ? yB0 : yA0;
                int oy1 = h5 ? yB1 : yA1;
                unsigned int wx0 = *(const unsigned int*)(base8 + (unsigned)(ox0 + sl4));
                unsigned int wx1 = *(const unsigned int*)(base8 + (unsigned)(ox1 + sl4));
                unsigned int wy0 = *(const unsigned int*)(base8 + (unsigned)(oy0 + sl4));
                unsigned int wy1 = *(const unsigned int*)(base8 + (unsigned)(oy1 + sl4));
                xL0 += __uint_as_float(wx0 << 16);
                xH0 += __uint_as_float(wx0 & 0xFFFF0000u);
                xL1 += __uint_as_float(wx1 << 16);
                xH1 += __uint_as_float(wx1 & 0xFFFF0000u);
                yL0 += __uint_as_float(wy0 << 16);
                yH0 += __uint_as_float(wy0 & 0xFFFF0000u);
                yL1 += __uint_as_float(wy1 << 16);
                yH1 += __uint_as_float(wy1 & 0xFFFF0000u);
            }
        }
    }
    float aLX = xL0 + xL1, aHX = xH0 + xH1;
    float aLY = yL0 + yL1, aHY = yH0 + yH1;
    // self rows: 32 consecutive dwords per half -> coalesced
    unsigned int wsX = *(const unsigned int*)(base8 + (unsigned)((nX << 7) + sl4));
    unsigned int wsY = *(const unsigned int*)(base8 + (unsigned)((nY << 7) + sl4));
    float nrX = norm[nX], nrY = norm[nY];
    float w0 = wpan[0];
    float w01 = wpan[0] * wpan[1];
    float vLX = fmaxf(nrX * (w0 * __uint_as_float(wsX << 16) + w01 * aLX), 0.0f);
    float vHX = fmaxf(nrX * (w0 * __uint_as_float(wsX & 0xFFFF0000u) + w01 * aHX), 0.0f);
    float vLY = fmaxf(nrY * (w0 * __uint_as_float(wsY << 16) + w01 * aLY), 0.0f);
    float vHY = fmaxf(nrY * (w0 * __uint_as_float(wsY & 0xFFFF0000u) + w01 * aHY), 0.0f);
    int c0 = 2 * sl;
    float4 wv0 = *(const float4*)(w44 + c0 * 4);
    float4 wv1 = *(const float4*)(w44 + (c0 + 1) * 4);
    float pX0 = vLX * wv0.x + vHX * wv1.x;
    float pX1 = vLX * wv0.y + vHX * wv1.y;
    float pX2 = vLX * wv0.z + vHX * wv1.z;
    float pX3 = vLX * wv0.w + vHX * wv1.w;
    float pY0 = vLY * wv0.x + vHY * wv1.x;
    float pY1 = vLY * wv0.y + vHY * wv1.y;
    float pY2 = vLY * wv0.z + vHY * wv1.z;
    float pY3 = vLY * wv0.w + vHY * wv1.w;
    for (int off = 16; off; off >>= 1) {     // reduce within the 32-lane half
        pX0 += __shfl_xor(pX0, off);
        pX1 += __shfl_xor(pX1, off);
        pX2 += __shfl_xor(pX2, off);
        pX3 += __shfl_xor(pX3, off);
        pY0 += __shfl_xor(pY0, off);
        pY1 += __shfl_xor(pY1, off);
        pY2 += __shfl_xor(pY2, off);
        pY3 += __shfl_xor(pY3, off);
    }
    if (sl == 0) {                           // lanes 0/32 write node X
        float4 bb = *(const float4*)bias4;
        *(float4*)(u + nX * 4) =
            make_float4(pX0 + bb.x, pX1 + bb.y, pX2 + bb.z, pX3 + bb.w);
    }
    if (sl == 1) {                           // lanes 1/33 write node Y
        float4 bb = *(const float4*)bias4;
        *(float4*)(u + nY * 4) =
            make_float4(pY0 + bb.x, pY1 + bb.y, pY2 + bb.z, pY3 + bb.w);
    }
}

// Layer-2 aggregate on the rank-4 table (x8-padded rows, branch-free):
// pq[n,j] = norm*(w0*u[n,j] + w01*sum u[src,j]).  csr holds s*128 byte offsets;
// u row start (float index) = s*4 = offset>>5.
__global__ void agg_pq4_kernel(const float* __restrict__ u, const int* __restrict__ row_start,
                               const int* __restrict__ row_pdeg,
                               const int* __restrict__ csr_src,
                               const float* __restrict__ norm,
                               const float* __restrict__ wpan, float* __restrict__ pq,
                               int n_nodes) {
    int t = threadIdx.x;
    int node = blockIdx.x * 64 + (t >> 2);
    int j = t & 3;
    if (node >= n_nodes) return;
    int e0 = row_start[node];
    int pd = row_pdeg[node];
    float acc = 0.0f;
    for (int e = 0; e < pd; e += 8) {
#pragma unroll
        for (int k = 0; k < 8; k++) {
            int so = csr_src[e0 + e + k];
            acc += u[(so >> 5) + j];
        }
    }
    float w0 = wpan[0];
    float w01 = wpan[0] * wpan[1];
    pq[node * 4 + j] = norm[node] * (w0 * u[node * 4 + j] + w01 * acc);
}

__global__ void edge_out_kernel(const int* __restrict__ src, const int* __restrict__ dst,
                                const float* __restrict__ pq, const float* __restrict__ bc,
                                float* __restrict__ out, int n_edges) {
    int e = blockIdx.x * blockDim.x + threadIdx.x;
    if (e >= n_edges) return;
    int r = src[e], c = dst[e];
    float2 p = *(const float2*)(pq + r * 4);
    float2 q = *(const float2*)(pq + c * 4 + 2);
    float2 o = make_float2(p.x + q.x + bc[0], p.y + q.y + bc[1]);
    *(float2*)(out + e * 2) = o;
}

extern "C" void kernel_launch(void* const* d_in, const int* in_sizes, int n_in,
                              void* d_out, int out_size, void* d_ws, size_t ws_size,
                              hipStream_t stream) {
    const float* x      = (const float*)d_in[0];
    const int*   eidx   = (const int*)d_in[1];
    const float* w1_lin = (const float*)d_in[2];
    const float* b1_lin = (const float*)d_in[3];
    const float* w1_pan = (const float*)d_in[4];
    const float* w2_lin = (const float*)d_in[5];
    const float* b2_lin = (const float*)d_in[6];
    const float* w2_pan = (const float*)d_in[7];
    const float* wc     = (const float*)d_in[8];
    const float* bc     = (const float*)d_in[9];
    float* out = (float*)d_out;

    const int* src = eidx;           // edge_index[0]
    const int* dst = eidx + NEDGES;  // edge_index[1]

    // ---- workspace carve-up (all 256B-aligned) ----
    char* ws = (char*)d_ws;
    size_t off = 0;
    auto carve = [&](size_t bytes) {
        char* p = ws + off;
        off = (off + bytes + 255) & ~(size_t)255;
        return p;
    };
    int*   bucket_fill = (int*)carve((size_t)NB * 4);
    int*   row_start = (int*)carve((size_t)NNODES * 4);
    int*   row_pdeg  = (int*)carve((size_t)NNODES * 4);
    unsigned int* staging = (unsigned int*)carve((size_t)NB * CAP * 4);   // 12.8 MB
    int*   csr_src  = (int*)carve(((size_t)NB * CAPE + 256) * 4);         // 12.8 MB + slack
    float* nrm      = (float*)carve((size_t)NNODES * 4);
    unsigned short* bufA = (unsigned short*)carve((size_t)(NNODES + 1) * HIDC * 2);
    float* u        = (float*)carve((size_t)(NNODES + 1) * 4 * 4);
    float* pq       = (float*)carve((size_t)NNODES * 4 * 4);
    float* w44      = (float*)carve((size_t)64 * 4 * 4);
    float* bias4    = (float*)carve((size_t)4 * 4);
    unsigned short* wTh = (unsigned short*)carve((size_t)HIDC * INC * 2); // 16 KB
    unsigned short* wTl = (unsigned short*)carve((size_t)HIDC * INC * 2); // 16 KB
    (void)ws_size; (void)in_sizes; (void)n_in; (void)out_size;

    hipMemsetAsync(bucket_fill, 0, (size_t)NB * 4, stream);

    // prep: wT bf16 hi/lo split + w44/bias4 fold + bufA sentinel row
    prep_w_kernel<<<32, 256, 0, stream>>>(w1_lin, wTh, wTl, w2_lin, b2_lin, wc,
                                          w44, bias4, bufA);

    // fat kernel: edge binning (first 391 blocks) || layer-1 MFMA GEMM (128 nodes/blk)
    fat_kernel<<<NBLK_FILL + NBLK_LIN, 256, 0, stream>>>(
        x, wTh, wTl, b1_lin, bufA, src, dst, bucket_fill, staging);

    // CSR build pass 2: x8-padded rows + row_start/pdeg + dedup + norm + scatter
    fill2_kernel<<<NB, 256, 0, stream>>>(bucket_fill, staging, csr_src, row_start, row_pdeg,
                                         nrm, NNODES);

    // layer 1 aggregate+relu fused with rank-4 projection -> u (4 nodes/wave)
    agg_h_kernel<<<(NNODES / 16), 256, 0, stream>>>(
        (const unsigned int*)bufA, row_start, row_pdeg, csr_src, nrm, w1_pan, w44, bias4,
        u, NNODES);

    // layer 2 aggregate on the rank-4 table
    agg_pq4_kernel<<<(NNODES + 63) / 64, 256, 0, stream>>>(
        u, row_start, row_pdeg, csr_src, nrm, w2_pan, pq, NNODES);

    // edge head: out[e] = p[src[e]] + q[dst[e]] + bc
    edge_out_kernel<<<NEDGES / 256, 256, 0, stream>>>(src, dst, pq, bc, out, NEDGES);
}

// Round 9
// 226.534 us; speedup vs baseline: 1.0036x; 1.0036x over previous
//
#include <hip/hip_runtime.h>
#include <hip/hip_bf16.h>

#define NNODES 100000
#define NEDGES 1600000
#define INC 128
#define HIDC 64
#define BSHIFT 7                      // 128 nodes per bucket
#define NB ((NNODES + 127) / 128)     // 782 buckets
#define TILE 4096                     // edges per fill1 workgroup (16/thread)
#define HSLOTS 4096                   // LDS hash slots in fill2 (16 KB)
#define CAP 4096                      // staging words per bucket (avg load ~2046)
#define CAPE 4096                     // csr words per bucket (rows padded to x8)
#define NBLK_FILL ((NEDGES + TILE - 1) / TILE)   // 391
#define NBLK_LIN ((NNODES + 63) / 64)            // 1563

typedef short bf16x8 __attribute__((ext_vector_type(8)));
typedef float f32x4 __attribute__((ext_vector_type(4)));

__device__ __forceinline__ float bf2f(unsigned short h) {
    return __uint_as_float((unsigned)h << 16);
}
__device__ __forceinline__ unsigned short f2bf(float f) {
    __hip_bfloat16 h = __float2bfloat16(f);
    return *(unsigned short*)&h;
}

// ---- prep kernel: w1 -> transposed bf16 hi/lo split; w44/bias4 fold; sentinel ----
__global__ __launch_bounds__(256) void prep_w_kernel(
        const float* __restrict__ w1, unsigned short* __restrict__ wTh,
        unsigned short* __restrict__ wTl,
        const float* __restrict__ w2_lin, const float* __restrict__ b2,
        const float* __restrict__ wc, float* __restrict__ w44,
        float* __restrict__ bias4, unsigned short* __restrict__ out) {
    int t = threadIdx.x;
    int e = blockIdx.x * 256 + t;            // 0..8191 over wT[64][128]
    int c = e >> 7, k = e & 127;
    float v = w1[k * 64 + c];
    unsigned short hi = f2bf(v);
    wTh[e] = hi;
    wTl[e] = f2bf(v - bf2f(hi));
    if (blockIdx.x == 0) {
        if (t < 16)   // zero sentinel row for padded gathers
            *(ushort4*)(out + (size_t)NNODES * 64 + t * 4) = make_ushort4(0, 0, 0, 0);
        int kk = t >> 2, j = t & 3;
        float a = 0.0f;
#pragma unroll 8
        for (int i = 0; i < 64; i++) {
            float w4 = (j < 2) ? wc[i * 2 + j] : wc[(64 + i) * 2 + (j - 2)];
            a += w2_lin[kk * 64 + i] * w4;
        }
        w44[kk * 4 + j] = a;
        if (kk == 0) {
            float bb4 = 0.0f;
            for (int i = 0; i < 64; i++) {
                float w4 = (j < 2) ? wc[i * 2 + j] : wc[(64 + i) * 2 + (j - 2)];
                bb4 += b2[i] * w4;
            }
            bias4[j] = bb4;
        }
    }
}

// ---- fat kernel: fill1 binning (blocks [0, NBLK_FILL)) + MFMA lin1 GEMM (rest) ----
// GEMM is bf16x3 error-compensated: x = xh+xl, w = wh+wl (bf16 each);
// h = xh*wh + xh*wl + xl*wh  (xl*wl term ~2^-18 rel, dropped).
// GEMM branch = R7-proven config (64 nodes/blk, hybrid staging: A direct
// global->reg, B LDS-staged/swizzled).
// R9 fix: fill1 hoists ALL 32 edge loads (16 src + 16 dst) into registers
// BEFORE any LDS work. Previously each LDS atomicAdd depended on that
// iteration's dst load -> 16 serialized ~900cy HBM round-trips per block;
// with 391 fill1 blocks all resident from t=0, that chain set the whole
// kernel's ~42us floor regardless of GEMM shape (R5/R7/R8 invariance).
__global__ __launch_bounds__(256, 5) void fat_kernel(
        const float* __restrict__ x,
        const unsigned short* __restrict__ wTh, const unsigned short* __restrict__ wTl,
        const float* __restrict__ b, unsigned short* __restrict__ out,
        const int* __restrict__ src, const int* __restrict__ dst,
        int* __restrict__ bucket_fill, unsigned int* __restrict__ staging) {
    __shared__ alignas(16) unsigned char smem[32768];   // union: fill1 22.6KB | B 32KB
    int t = threadIdx.x;
    if (blockIdx.x < NBLK_FILL) {
        // ---------------- fill1 branch ----------------
        int* cnt = (int*)smem;
        int* basepos = cnt + NB;
        unsigned int* svl = (unsigned int*)(basepos + NB);   // 4096 words = TILE
        for (int i = t; i < NB; i += 256) cnt[i] = 0;
        int tile0 = blockIdx.x * TILE;
        // hoist: issue all 32 independent edge loads up-front (1 latency, not 16)
        int se[16], de[16];
#pragma unroll
        for (int i = 0; i < 16; i++) {
            int e = tile0 + i * 256 + t;
            if (e < NEDGES) { se[i] = src[e]; de[i] = dst[e]; }
            else            { se[i] = -1;     de[i] = 0; }
        }
        __syncthreads();
        int meta[16];
#pragma unroll
        for (int i = 0; i < 16; i++) {
            meta[i] = -1;
            if (se[i] >= 0) {
                int bkt = de[i] >> BSHIFT;
                int r = atomicAdd(&cnt[bkt], 1);     // < TILE = 4096 (12 bits)
                meta[i] = (bkt << 12) | r;
                svl[i * 256 + t] = ((unsigned)(de[i] & 127) << 17) | (unsigned)se[i];
            }
        }
        __syncthreads();
        for (int i = t; i < NB; i += 256) {
            int c = cnt[i];
            int g = (c > 0) ? atomicAdd(&bucket_fill[i], c) : 0;
            basepos[i] = (i << 12) + g;              // staging region = [i*CAP, ...)
        }
        __syncthreads();
#pragma unroll
        for (int i = 0; i < 16; i++) {
            if (meta[i] >= 0) {
                int bkt = meta[i] >> 12, r = meta[i] & 4095;
                staging[basepos[bkt] + r] = svl[i * 256 + t];
            }
        }
    } else {
        // ------- hybrid MFMA GEMM branch: 64 nodes x 64 cols, K=128 -------
        unsigned short* s_bh = (unsigned short*)smem;        // [64][128] swizzled
        unsigned short* s_bl = s_bh + 64 * 128;
        int node0 = (blockIdx.x - NBLK_FILL) * 64;
        int l = t & 63, wv = t >> 6;
        int mr = l & 15, g = l >> 4;
        int arow = wv * 16 + mr;
        int node = node0 + arow;
        bool vr = (node < NNODES);
        const float* xr = x + (size_t)node * INC;
        // issue A loads up-front (8 independent float4s -> in flight together)
        float4 vx[8];
#pragma unroll
        for (int ks = 0; ks < 4; ks++) {
            int k0 = ks * 32 + g * 8;
            vx[2 * ks]     = vr ? *(const float4*)(xr + k0)
                                : make_float4(0.f, 0.f, 0.f, 0.f);
            vx[2 * ks + 1] = vr ? *(const float4*)(xr + k0 + 4)
                                : make_float4(0.f, 0.f, 0.f, 0.f);
        }
        // cooperative B staging: 1024+1024 uint4s, coalesced, swizzled store
#pragma unroll
        for (int i = 0; i < 4; i++) {
            int e = i * 256 + t;                     // ushort8 chunk of wT[64][128]
            uint4 vh = *(const uint4*)(wTh + (size_t)e * 8);
            uint4 vl = *(const uint4*)(wTl + (size_t)e * 8);
            int col = e >> 4, k0 = (e & 15) * 8;
            int ke = k0 ^ ((col & 7) << 3);
            *(uint4*)&s_bh[col * 128 + ke] = vh;
            *(uint4*)&s_bl[col * 128 + ke] = vl;
        }
        __syncthreads();
        f32x4 acc[4] = {{0.f, 0.f, 0.f, 0.f}, {0.f, 0.f, 0.f, 0.f},
                        {0.f, 0.f, 0.f, 0.f}, {0.f, 0.f, 0.f, 0.f}};
#pragma unroll
        for (int ks = 0; ks < 4; ks++) {
            int k0 = ks * 32 + g * 8;
            float xv[8] = {vx[2 * ks].x, vx[2 * ks].y, vx[2 * ks].z, vx[2 * ks].w,
                           vx[2 * ks + 1].x, vx[2 * ks + 1].y,
                           vx[2 * ks + 1].z, vx[2 * ks + 1].w};
            bf16x8 ah, al;
#pragma unroll
            for (int j = 0; j < 8; j++) {
                unsigned short h = f2bf(xv[j]);
                ah[j] = (short)h;
                al[j] = (short)f2bf(xv[j] - bf2f(h));
            }
#pragma unroll
            for (int cb = 0; cb < 4; cb++) {
                int col = cb * 16 + mr;
                int ko = k0 ^ ((col & 7) << 3);
                bf16x8 bh = *(const bf16x8*)&s_bh[col * 128 + ko];
                bf16x8 bl = *(const bf16x8*)&s_bl[col * 128 + ko];
                acc[cb] = __builtin_amdgcn_mfma_f32_16x16x32_bf16(ah, bh, acc[cb], 0, 0, 0);
                acc[cb] = __builtin_amdgcn_mfma_f32_16x16x32_bf16(ah, bl, acc[cb], 0, 0, 0);
                acc[cb] = __builtin_amdgcn_mfma_f32_16x16x32_bf16(al, bh, acc[cb], 0, 0, 0);
            }
        }
#pragma unroll
        for (int cb = 0; cb < 4; cb++) {
            int col = cb * 16 + mr;
            float bb = b[col];
#pragma unroll
            for (int r = 0; r < 4; r++) {
                int n2 = node0 + wv * 16 + g * 4 + r;
                if (n2 < NNODES)
                    out[(size_t)n2 * 64 + col] = f2bf(acc[cb][r] + bb);
            }
        }
    }
}

// fill pass 2: one WG per 128-node bucket, fixed csr region [b*CAPE, ...).
// Rows padded to x8 with sentinel n_nodes (points at the zero row).
// csr_src stores BYTE offsets (s*128) of the 128-B bufA rows.
__global__ __launch_bounds__(256) void fill2_kernel(
        const int* __restrict__ bucket_fill, const unsigned int* __restrict__ staging,
        int* __restrict__ csr_src, int* __restrict__ row_start,
        int* __restrict__ row_pdeg, float* __restrict__ norm, int n_nodes) {
    __shared__ int cnt[128];
    __shared__ int dcount[128];
    __shared__ int off[128];
    __shared__ int pscan[128];
    __shared__ unsigned short rank16[CAP];   // 8 KB
    __shared__ unsigned int ht[HSLOTS];      // 16 KB
    int t = threadIdx.x;
    int b = blockIdx.x;
    int node0 = b << BSHIFT;
    int nn = min(128, n_nodes - node0);
    if (t < 128) { cnt[t] = 0; dcount[t] = 0; }
    {
        uint4* h4 = (uint4*)ht;
        uint4 ff = make_uint4(0xFFFFFFFFu, 0xFFFFFFFFu, 0xFFFFFFFFu, 0xFFFFFFFFu);
        for (int i = t; i < HSLOTS / 4; i += 256) h4[i] = ff;
    }
    __syncthreads();
    int start = b << 12;
    int total = bucket_fill[b];
    // phase A: count + rank + dedup
    for (int li = t; li < total; li += 256) {
        unsigned int w = staging[start + li];
        int s = (int)(w & 0x1FFFFu);
        int dl = (int)(w >> 17);
        int r = atomicAdd(&cnt[dl], 1);
        rank16[li] = (unsigned short)r;
        if (s != node0 + dl) {  // self-loops merge with the I-diagonal
            unsigned int slot = ((w * 2654435761u) >> 13) & (HSLOTS - 1);
            while (true) {
                unsigned int prev = atomicCAS(&ht[slot], 0xFFFFFFFFu, w);
                if (prev == 0xFFFFFFFFu) { atomicAdd(&dcount[dl], 1); break; }
                if (prev == w) break;
                slot = (slot + 1) & (HSLOTS - 1);
            }
        }
    }
    __syncthreads();
    // exclusive prefix of x8-padded counts -> csr offsets within [b*CAPE, ...)
    int cv = 0, pv = 0;
    if (t < 128) {
        cv = cnt[t];
        pv = (cv + 7) & ~7;
        pscan[t] = pv;
    }
    __syncthreads();
    for (int o = 1; o < 128; o <<= 1) {
        int xx = (t >= o && t < 128) ? pscan[t - o] : 0;
        __syncthreads();
        if (t < 128) pscan[t] += xx;
        __syncthreads();
    }
    if (t < 128) off[t] = b * CAPE + pscan[t] - pv;
    __syncthreads();
    if (t < nn) {
        row_start[node0 + t] = off[t];
        row_pdeg[node0 + t] = pv;
        norm[node0 + t] = 1.0f / (1.0f + (float)dcount[t]);
    }
    // sentinel-pad the tail of each row (byte offset of the zero row)
    if (t < 128)
        for (int k = cv; k < pv; k++) csr_src[off[t] + k] = n_nodes << 7;
    // phase B: scatter csr (byte offsets: s*128)
    for (int li = t; li < total; li += 256) {
        unsigned int w = staging[start + li];
        int s = (int)(w & 0x1FFFFu);
        int dl = (int)(w >> 17);
        csr_src[off[dl] + (int)rank16[li]] = s << 7;
    }
}

// Four nodes per wave: lanes 0-31 own nodes {4q, 4q+1}, lanes 32-63 own
// {4q+2, 4q+3}. Two independent edge streams (X=even node, Y=odd node) per
// half, each keeping the proven wd0/wd1 edge-pairing -> MLP=4 dword gathers
// in flight at the same ~4 VALU/edge. Each dword wave-load still fetches
// exactly 2 full 128-B h1 rows. 100000 = 4*25000: grid exact, no guards.
// csr holds pre-shifted byte offsets (1 v_add addressing); tail slots clamp
// to the sentinel zero row (L1-resident). Fused PAN combine + relu + rank-4
// projection -> u; h1 never hits global memory.
__global__ void agg_h_kernel(const unsigned int* __restrict__ lin32,
                             const int* __restrict__ row_start,
                             const int* __restrict__ row_pdeg,
                             const int* __restrict__ csr_src,
                             const float* __restrict__ norm,
                             const float* __restrict__ wpan, const float* __restrict__ w44,
                             const float* __restrict__ bias4, float* __restrict__ u,
                             int n_nodes) {
    int t = threadIdx.x;
    int lane = t & 63;
    int sl = lane & 31;                      // channel dword / edge slot
    int h5 = lane >> 5;                      // half: owns nodes 4q+2*h5 + {0,1}
    int quad = blockIdx.x * 4 + (t >> 6);
    if (blockIdx.x == 0 && t < 4) u[n_nodes * 4 + t] = 0.0f;  // zero row for agg_pq4 pads
    int nX = quad * 4 + h5 * 2;
    int nY = nX + 1;
    int e0X = row_start[nX], pdX = row_pdeg[nX];
    int e0Y = row_start[nY], pdY = row_pdeg[nY];
    int pm = max(pdX, pdY);
    int pmax = max(pm, __shfl_xor(pm, 32));  // wave-uniform chunk bound
    int sentB = n_nodes << 7;                // byte offset of the zero row
    unsigned sl4 = (unsigned)sl * 4;
    const char* base8 = (const char*)lin32;
    float xL0 = 0.f, xH0 = 0.f, xL1 = 0.f, xH1 = 0.f;
    float yL0 = 0.f, yH0 = 0.f, yL1 = 0.f, yH1 = 0.f;
    for (int base = 0; base < pmax; base += 32) {
        int li = base + sl;
        int soX = (li < pdX) ? csr_src[e0X + li] : sentB;
        int soY = (li < pdY) ? csr_src[e0Y + li] : sentB;
        int m = min(32, pmax - base);        // wave-uniform, multiple of 8
#pragma unroll
        for (int i = 0; i < 32; i += 2) {
            if (i < m) {
                int xA0 = __builtin_amdgcn_readlane(soX, i);
                int xB0 = __builtin_amdgcn_readlane(soX, 32 + i);
                int xA1 = __builtin_amdgcn_readlane(soX, i + 1);
                int xB1 = __builtin_amdgcn_readlane(soX, 33 + i);
                int yA0 = __builtin_amdgcn_readlane(soY, i);
                int yB0 = __builtin_amdgcn_readlane(soY, 32 + i);
                int yA1 = __builtin_amdgcn_readlane(soY, i + 1);
                int yB1 = __builtin_amdgcn_readlane(soY, 33 + i);
                int ox0 = h5 ? xB0 : xA0;
                int ox1 = h5 ? xB1 : xA1;
                int oy0 = h5 ? yB0 : yA0;
                int oy1 = h5 ? yB1 : yA1;
                unsigned int wx0 = *(const unsigned int*)(base8 + (unsigned)(ox0 + sl4));
                unsigned int wx1 = *(const unsigned int*)(base8 + (unsigned)(ox1 + sl4));
                unsigned int wy0 = *(const unsigned int*)(base8 + (unsigned)(oy0 + sl4));
                unsigned int wy1 = *(const unsigned int*)(base8 + (unsigned)(oy1 + sl4));
                xL0 += __uint_as_float(wx0 << 16);
                xH0 += __uint_as_float(wx0 & 0xFFFF0000u);
                xL1 += __uint_as_float(wx1 << 16);
                xH1 += __uint_as_float(wx1 & 0xFFFF0000u);
                yL0 += __uint_as_float(wy0 << 16);
                yH0 += __uint_as_float(wy0 & 0xFFFF0000u);
                yL1 += __uint_as_float(wy1 << 16);
                yH1 += __uint_as_float(wy1 & 0xFFFF0000u);
            }
        }
    }
    float aLX = xL0 + xL1, aHX = xH0 + xH1;
    float aLY = yL0 + yL1, aHY = yH0 + yH1;
    // self rows: 32 consecutive dwords per half -> coalesced
    unsigned int wsX = *(const unsigned int*)(base8 + (unsigned)((nX << 7) + sl4));
    unsigned int wsY = *(const unsigned int*)(base8 + (unsigned)((nY << 7) + sl4));
    float nrX = norm[nX], nrY = norm[nY];
    float w0 = wpan[0];
    float w01 = wpan[0] * wpan[1];
    float vLX = fmaxf(nrX * (w0 * __uint_as_float(wsX << 16) + w01 * aLX), 0.0f);
    float vHX = fmaxf(nrX * (w0 * __uint_as_float(wsX & 0xFFFF0000u) + w01 * aHX), 0.0f);
    float vLY = fmaxf(nrY * (w0 * __uint_as_float(wsY << 16) + w01 * aLY), 0.0f);
    float vHY = fmaxf(nrY * (w0 * __uint_as_float(wsY & 0xFFFF0000u) + w01 * aHY), 0.0f);
    int c0 = 2 * sl;
    float4 wv0 = *(const float4*)(w44 + c0 * 4);
    float4 wv1 = *(const float4*)(w44 + (c0 + 1) * 4);
    float pX0 = vLX * wv0.x + vHX * wv1.x;
    float pX1 = vLX * wv0.y + vHX * wv1.y;
    float pX2 = vLX * wv0.z + vHX * wv1.z;
    float pX3 = vLX * wv0.w + vHX * wv1.w;
    float pY0 = vLY * wv0.x + vHY * wv1.x;
    float pY1 = vLY * wv0.y + vHY * wv1.y;
    float pY2 = vLY * wv0.z + vHY * wv1.z;
    float pY3 = vLY * wv0.w + vHY * wv1.w;
    for (int off = 16; off; off >>= 1) {     // reduce within the 32-lane half
        pX0 += __shfl_xor(pX0, off);
        pX1 += __shfl_xor(pX1, off);
        pX2 += __shfl_xor(pX2, off);
        pX3 += __shfl_xor(pX3, off);
        pY0 += __shfl_xor(pY0, off);
        pY1 += __shfl_xor(pY1, off);
        pY2 += __shfl_xor(pY2, off);
        pY3 += __shfl_xor(pY3, off);
    }
    if (sl == 0) {                           // lanes 0/32 write node X
        float4 bb = *(const float4*)bias4;
        *(float4*)(u + nX * 4) =
            make_float4(pX0 + bb.x, pX1 + bb.y, pX2 + bb.z, pX3 + bb.w);
    }
    if (sl == 1) {                           // lanes 1/33 write node Y
        float4 bb = *(const float4*)bias4;
        *(float4*)(u + nY * 4) =
            make_float4(pY0 + bb.x, pY1 + bb.y, pY2 + bb.z, pY3 + bb.w);
    }
}

// Layer-2 aggregate on the rank-4 table (x8-padded rows, branch-free):
// pq[n,j] = norm*(w0*u[n,j] + w01*sum u[src,j]).  csr holds s*128 byte offsets;
// u row start (float index) = s*4 = offset>>5.
__global__ void agg_pq4_kernel(const float* __restrict__ u, const int* __restrict__ row_start,
                               const int* __restrict__ row_pdeg,
                               const int* __restrict__ csr_src,
                               const float* __restrict__ norm,
                               const float* __restrict__ wpan, float* __restrict__ pq,
                               int n_nodes) {
    int t = threadIdx.x;
    int node = blockIdx.x * 64 + (t >> 2);
    int j = t & 3;
    if (node >= n_nodes) return;
    int e0 = row_start[node];
    int pd = row_pdeg[node];
    float acc = 0.0f;
    for (int e = 0; e < pd; e += 8) {
#pragma unroll
        for (int k = 0; k < 8; k++) {
            int so = csr_src[e0 + e + k];
            acc += u[(so >> 5) + j];
        }
    }
    float w0 = wpan[0];
    float w01 = wpan[0] * wpan[1];
    pq[node * 4 + j] = norm[node] * (w0 * u[node * 4 + j] + w01 * acc);
}

__global__ void edge_out_kernel(const int* __restrict__ src, const int* __restrict__ dst,
                                const float* __restrict__ pq, const float* __restrict__ bc,
                                float* __restrict__ out, int n_edges) {
    int e = blockIdx.x * blockDim.x + threadIdx.x;
    if (e >= n_edges) return;
    int r = src[e], c = dst[e];
    float2 p = *(const float2*)(pq + r * 4);
    float2 q = *(const float2*)(pq + c * 4 + 2);
    float2 o = make_float2(p.x + q.x + bc[0], p.y + q.y + bc[1]);
    *(float2*)(out + e * 2) = o;
}

extern "C" void kernel_launch(void* const* d_in, const int* in_sizes, int n_in,
                              void* d_out, int out_size, void* d_ws, size_t ws_size,
                              hipStream_t stream) {
    const float* x      = (const float*)d_in[0];
    const int*   eidx   = (const int*)d_in[1];
    const float* w1_lin = (const float*)d_in[2];
    const float* b1_lin = (const float*)d_in[3];
    const float* w1_pan = (const float*)d_in[4];
    const float* w2_lin = (const float*)d_in[5];
    const float* b2_lin = (const float*)d_in[6];
    const float* w2_pan = (const float*)d_in[7];
    const float* wc     = (const float*)d_in[8];
    const float* bc     = (const float*)d_in[9];
    float* out = (float*)d_out;

    const int* src = eidx;           // edge_index[0]
    const int* dst = eidx + NEDGES;  // edge_index[1]

    // ---- workspace carve-up (all 256B-aligned) ----
    char* ws = (char*)d_ws;
    size_t off = 0;
    auto carve = [&](size_t bytes) {
        char* p = ws + off;
        off = (off + bytes + 255) & ~(size_t)255;
        return p;
    };
    int*   bucket_fill = (int*)carve((size_t)NB * 4);
    int*   row_start = (int*)carve((size_t)NNODES * 4);
    int*   row_pdeg  = (int*)carve((size_t)NNODES * 4);
    unsigned int* staging = (unsigned int*)carve((size_t)NB * CAP * 4);   // 12.8 MB
    int*   csr_src  = (int*)carve(((size_t)NB * CAPE + 256) * 4);         // 12.8 MB + slack
    float* nrm      = (float*)carve((size_t)NNODES * 4);
    unsigned short* bufA = (unsigned short*)carve((size_t)(NNODES + 1) * HIDC * 2);
    float* u        = (float*)carve((size_t)(NNODES + 1) * 4 * 4);
    float* pq       = (float*)carve((size_t)NNODES * 4 * 4);
    float* w44      = (float*)carve((size_t)64 * 4 * 4);
    float* bias4    = (float*)carve((size_t)4 * 4);
    unsigned short* wTh = (unsigned short*)carve((size_t)HIDC * INC * 2); // 16 KB
    unsigned short* wTl = (unsigned short*)carve((size_t)HIDC * INC * 2); // 16 KB
    (void)ws_size; (void)in_sizes; (void)n_in; (void)out_size;

    hipMemsetAsync(bucket_fill, 0, (size_t)NB * 4, stream);

    // prep: wT bf16 hi/lo split + w44/bias4 fold + bufA sentinel row
    prep_w_kernel<<<32, 256, 0, stream>>>(w1_lin, wTh, wTl, w2_lin, b2_lin, wc,
                                          w44, bias4, bufA);

    // fat kernel: edge binning (hoisted loads) || layer-1 MFMA GEMM (R7 config)
    fat_kernel<<<NBLK_FILL + NBLK_LIN, 256, 0, stream>>>(
        x, wTh, wTl, b1_lin, bufA, src, dst, bucket_fill, staging);

    // CSR build pass 2: x8-padded rows + row_start/pdeg + dedup + norm + scatter
    fill2_kernel<<<NB, 256, 0, stream>>>(bucket_fill, staging, csr_src, row_start, row_pdeg,
                                         nrm, NNODES);

    // layer 1 aggregate+relu fused with rank-4 projection -> u (4 nodes/wave)
    agg_h_kernel<<<(NNODES / 16), 256, 0, stream>>>(
        (const unsigned int*)bufA, row_start, row_pdeg, csr_src, nrm, w1_pan, w44, bias4,
        u, NNODES);

    // layer 2 aggregate on the rank-4 table
    agg_pq4_kernel<<<(NNODES + 63) / 64, 256, 0, stream>>>(
        u, row_start, row_pdeg, csr_src, nrm, w2_pan, pq, NNODES);

    // edge head: out[e] = p[src[e]] + q[dst[e]] + bc
    edge_out_kernel<<<NEDGES / 256, 256, 0, stream>>>(src, dst, pq, bc, out, NEDGES);
}

// Round 10
// 222.351 us; speedup vs baseline: 1.0225x; 1.0188x over previous
//
#include <hip/hip_runtime.h>
#include <hip/hip_bf16.h>

#define NNODES 100000
#define NEDGES 1600000
#define INC 128
#define HIDC 64
#define BSHIFT 7                      // 128 nodes per bucket
#define NB ((NNODES + 127) / 128)     // 782 buckets
#define TILE 4096                     // edges per fill1 workgroup (16/thread)
#define HSLOTS 4096                   // LDS hash slots in fill2 (16 KB)
#define CAP 4096                      // staging words per bucket (avg load ~2046)
#define CAPE 4096                     // csr words per bucket (rows padded to x8)
#define NBLK_FILL ((NEDGES + TILE - 1) / TILE)   // 391
#define NBLK_LIN ((NNODES + 63) / 64)            // 1563
#define NPREP 32                      // prep blocks in kernel 1

typedef short bf16x8 __attribute__((ext_vector_type(8)));
typedef float f32x4 __attribute__((ext_vector_type(4)));

__device__ __forceinline__ float bf2f(unsigned short h) {
    return __uint_as_float((unsigned)h << 16);
}
__device__ __forceinline__ unsigned short f2bf(float f) {
    __hip_bfloat16 h = __float2bfloat16(f);
    return *(unsigned short*)&h;
}

// ---- kernel 1: prep (blocks [0,32)) + fill1 binning (blocks [32, 32+391)) ----
// prep: w1 -> transposed bf16 hi/lo split; w44/bias4 fold; bufA sentinel row.
// fill1: bucket-bin edges into staging (hoisted edge loads, LDS count+rank).
// Independent work merged to overlap prep under fill1 and save a launch.
__global__ __launch_bounds__(256) void prepfill1_kernel(
        const float* __restrict__ w1, unsigned short* __restrict__ wTh,
        unsigned short* __restrict__ wTl,
        const float* __restrict__ w2_lin, const float* __restrict__ b2,
        const float* __restrict__ wc, float* __restrict__ w44,
        float* __restrict__ bias4, unsigned short* __restrict__ out,
        const int* __restrict__ src, const int* __restrict__ dst,
        int* __restrict__ bucket_fill, unsigned int* __restrict__ staging) {
    __shared__ alignas(16) unsigned char smem[22528];   // fill1: cnt+basepos+svl
    int t = threadIdx.x;
    if (blockIdx.x < NPREP) {
        // ---------------- prep branch ----------------
        int e = blockIdx.x * 256 + t;            // 0..8191 over wT[64][128]
        int c = e >> 7, k = e & 127;
        float v = w1[k * 64 + c];
        unsigned short hi = f2bf(v);
        wTh[e] = hi;
        wTl[e] = f2bf(v - bf2f(hi));
        if (blockIdx.x == 0) {
            if (t < 16)   // zero sentinel row for padded gathers
                *(ushort4*)(out + (size_t)NNODES * 64 + t * 4) = make_ushort4(0, 0, 0, 0);
            int kk = t >> 2, j = t & 3;
            float a = 0.0f;
#pragma unroll 8
            for (int i = 0; i < 64; i++) {
                float w4 = (j < 2) ? wc[i * 2 + j] : wc[(64 + i) * 2 + (j - 2)];
                a += w2_lin[kk * 64 + i] * w4;
            }
            w44[kk * 4 + j] = a;
            if (kk == 0) {
                float bb4 = 0.0f;
                for (int i = 0; i < 64; i++) {
                    float w4 = (j < 2) ? wc[i * 2 + j] : wc[(64 + i) * 2 + (j - 2)];
                    bb4 += b2[i] * w4;
                }
                bias4[j] = bb4;
            }
        }
    } else {
        // ---------------- fill1 branch ----------------
        int* cnt = (int*)smem;
        int* basepos = cnt + NB;
        unsigned int* svl = (unsigned int*)(basepos + NB);   // 4096 words = TILE
        for (int i = t; i < NB; i += 256) cnt[i] = 0;
        int tile0 = (blockIdx.x - NPREP) * TILE;
        // hoist: issue all 32 independent edge loads up-front
        int se[16], de[16];
#pragma unroll
        for (int i = 0; i < 16; i++) {
            int e = tile0 + i * 256 + t;
            if (e < NEDGES) { se[i] = src[e]; de[i] = dst[e]; }
            else            { se[i] = -1;     de[i] = 0; }
        }
        __syncthreads();
        int meta[16];
#pragma unroll
        for (int i = 0; i < 16; i++) {
            meta[i] = -1;
            if (se[i] >= 0) {
                int bkt = de[i] >> BSHIFT;
                int r = atomicAdd(&cnt[bkt], 1);     // < TILE = 4096 (12 bits)
                meta[i] = (bkt << 12) | r;
                svl[i * 256 + t] = ((unsigned)(de[i] & 127) << 17) | (unsigned)se[i];
            }
        }
        __syncthreads();
        for (int i = t; i < NB; i += 256) {
            int c = cnt[i];
            int g = (c > 0) ? atomicAdd(&bucket_fill[i], c) : 0;
            basepos[i] = (i << 12) + g;              // staging region = [i*CAP, ...)
        }
        __syncthreads();
#pragma unroll
        for (int i = 0; i < 16; i++) {
            if (meta[i] >= 0) {
                int bkt = meta[i] >> 12, r = meta[i] & 4095;
                staging[basepos[bkt] + r] = svl[i * 256 + t];
            }
        }
    }
}

// ---- kernel 2: MFMA lin1 GEMM (blocks [0,1563)) + fill2 CSR build (rest) ----
// GEMM is bf16x3 error-compensated: x = xh+xl, w = wh+wl (bf16 each);
// h = xh*wh + xh*wl + xl*wh. Hybrid staging (R7-proven): A direct global->reg,
// B LDS-staged/swizzled. GEMM blocks dispatched FIRST (flood CUs with MFMA
// work); fill2's 782 latency/LDS-atomic blocks trickle in as GEMM retires --
// the overlap the old fused fat kernel had backwards (fill1-first).
// fill2: one WG per 128-node bucket; rows x8-padded with sentinel; csr_src
// stores BYTE offsets (s*128) of the 128-B bufA rows.
__global__ __launch_bounds__(256, 5) void gemmfill2_kernel(
        const float* __restrict__ x,
        const unsigned short* __restrict__ wTh, const unsigned short* __restrict__ wTl,
        const float* __restrict__ b, unsigned short* __restrict__ out,
        const int* __restrict__ bucket_fill, const unsigned int* __restrict__ staging,
        int* __restrict__ csr_src, int* __restrict__ row_start,
        int* __restrict__ row_pdeg, float* __restrict__ norm, int n_nodes) {
    __shared__ alignas(16) unsigned char smem[32768];   // union: B 32KB | fill2 26.6KB
    int t = threadIdx.x;
    if (blockIdx.x < NBLK_LIN) {
        // ------- hybrid MFMA GEMM branch: 64 nodes x 64 cols, K=128 -------
        unsigned short* s_bh = (unsigned short*)smem;        // [64][128] swizzled
        unsigned short* s_bl = s_bh + 64 * 128;
        int node0 = blockIdx.x * 64;
        int l = t & 63, wv = t >> 6;
        int mr = l & 15, g = l >> 4;
        int arow = wv * 16 + mr;
        int node = node0 + arow;
        bool vr = (node < NNODES);
        const float* xr = x + (size_t)node * INC;
        // issue A loads up-front (8 independent float4s -> in flight together)
        float4 vx[8];
#pragma unroll
        for (int ks = 0; ks < 4; ks++) {
            int k0 = ks * 32 + g * 8;
            vx[2 * ks]     = vr ? *(const float4*)(xr + k0)
                                : make_float4(0.f, 0.f, 0.f, 0.f);
            vx[2 * ks + 1] = vr ? *(const float4*)(xr + k0 + 4)
                                : make_float4(0.f, 0.f, 0.f, 0.f);
        }
        // cooperative B staging: 1024+1024 uint4s, coalesced, swizzled store
#pragma unroll
        for (int i = 0; i < 4; i++) {
            int e = i * 256 + t;                     // ushort8 chunk of wT[64][128]
            uint4 vh = *(const uint4*)(wTh + (size_t)e * 8);
            uint4 vl = *(const uint4*)(wTl + (size_t)e * 8);
            int col = e >> 4, k0 = (e & 15) * 8;
            int ke = k0 ^ ((col & 7) << 3);
            *(uint4*)&s_bh[col * 128 + ke] = vh;
            *(uint4*)&s_bl[col * 128 + ke] = vl;
        }
        __syncthreads();
        f32x4 acc[4] = {{0.f, 0.f, 0.f, 0.f}, {0.f, 0.f, 0.f, 0.f},
                        {0.f, 0.f, 0.f, 0.f}, {0.f, 0.f, 0.f, 0.f}};
#pragma unroll
        for (int ks = 0; ks < 4; ks++) {
            int k0 = ks * 32 + g * 8;
            float xv[8] = {vx[2 * ks].x, vx[2 * ks].y, vx[2 * ks].z, vx[2 * ks].w,
                           vx[2 * ks + 1].x, vx[2 * ks + 1].y,
                           vx[2 * ks + 1].z, vx[2 * ks + 1].w};
            bf16x8 ah, al;
#pragma unroll
            for (int j = 0; j < 8; j++) {
                unsigned short h = f2bf(xv[j]);
                ah[j] = (short)h;
                al[j] = (short)f2bf(xv[j] - bf2f(h));
            }
#pragma unroll
            for (int cb = 0; cb < 4; cb++) {
                int col = cb * 16 + mr;
                int ko = k0 ^ ((col & 7) << 3);
                bf16x8 bh = *(const bf16x8*)&s_bh[col * 128 + ko];
                bf16x8 bl = *(const bf16x8*)&s_bl[col * 128 + ko];
                acc[cb] = __builtin_amdgcn_mfma_f32_16x16x32_bf16(ah, bh, acc[cb], 0, 0, 0);
                acc[cb] = __builtin_amdgcn_mfma_f32_16x16x32_bf16(ah, bl, acc[cb], 0, 0, 0);
                acc[cb] = __builtin_amdgcn_mfma_f32_16x16x32_bf16(al, bh, acc[cb], 0, 0, 0);
            }
        }
#pragma unroll
        for (int cb = 0; cb < 4; cb++) {
            int col = cb * 16 + mr;
            float bb = b[col];
#pragma unroll
            for (int r = 0; r < 4; r++) {
                int n2 = node0 + wv * 16 + g * 4 + r;
                if (n2 < NNODES)
                    out[(size_t)n2 * 64 + col] = f2bf(acc[cb][r] + bb);
            }
        }
    } else {
        // ---------------- fill2 branch ----------------
        int* cnt = (int*)smem;                   // 128 ints
        int* dcount = cnt + 128;
        int* off = dcount + 128;
        int* pscan = off + 128;
        unsigned short* rank16 = (unsigned short*)(pscan + 128);   // 8 KB
        unsigned int* ht = (unsigned int*)(rank16 + CAP);          // 16 KB
        int b2k = blockIdx.x - NBLK_LIN;
        int node0 = b2k << BSHIFT;
        int nn = min(128, n_nodes - node0);
        if (t < 128) { cnt[t] = 0; dcount[t] = 0; }
        {
            uint4* h4 = (uint4*)ht;
            uint4 ff = make_uint4(0xFFFFFFFFu, 0xFFFFFFFFu, 0xFFFFFFFFu, 0xFFFFFFFFu);
            for (int i = t; i < HSLOTS / 4; i += 256) h4[i] = ff;
        }
        __syncthreads();
        int start = b2k << 12;
        int total = bucket_fill[b2k];
        // phase A: count + rank + dedup
        for (int li = t; li < total; li += 256) {
            unsigned int w = staging[start + li];
            int s = (int)(w & 0x1FFFFu);
            int dl = (int)(w >> 17);
            int r = atomicAdd(&cnt[dl], 1);
            rank16[li] = (unsigned short)r;
            if (s != node0 + dl) {  // self-loops merge with the I-diagonal
                unsigned int slot = ((w * 2654435761u) >> 13) & (HSLOTS - 1);
                while (true) {
                    unsigned int prev = atomicCAS(&ht[slot], 0xFFFFFFFFu, w);
                    if (prev == 0xFFFFFFFFu) { atomicAdd(&dcount[dl], 1); break; }
                    if (prev == w) break;
                    slot = (slot + 1) & (HSLOTS - 1);
                }
            }
        }
        __syncthreads();
        // exclusive prefix of x8-padded counts -> csr offsets within [b*CAPE, ...)
        int cv = 0, pv = 0;
        if (t < 128) {
            cv = cnt[t];
            pv = (cv + 7) & ~7;
            pscan[t] = pv;
        }
        __syncthreads();
        for (int o = 1; o < 128; o <<= 1) {
            int xx = (t >= o && t < 128) ? pscan[t - o] : 0;
            __syncthreads();
            if (t < 128) pscan[t] += xx;
            __syncthreads();
        }
        if (t < 128) off[t] = b2k * CAPE + pscan[t] - pv;
        __syncthreads();
        if (t < nn) {
            row_start[node0 + t] = off[t];
            row_pdeg[node0 + t] = pv;
            norm[node0 + t] = 1.0f / (1.0f + (float)dcount[t]);
        }
        // sentinel-pad the tail of each row (byte offset of the zero row)
        if (t < 128)
            for (int k = cv; k < pv; k++) csr_src[off[t] + k] = n_nodes << 7;
        // phase B: scatter csr (byte offsets: s*128)
        for (int li = t; li < total; li += 256) {
            unsigned int w = staging[start + li];
            int s = (int)(w & 0x1FFFFu);
            int dl = (int)(w >> 17);
            csr_src[off[dl] + (int)rank16[li]] = s << 7;
        }
    }
}

// Four nodes per wave: lanes 0-31 own nodes {4q, 4q+1}, lanes 32-63 own
// {4q+2, 4q+3}. Two independent edge streams (X=even node, Y=odd node) per
// half, each keeping the proven wd0/wd1 edge-pairing -> MLP=4 dword gathers
// in flight at the same ~4 VALU/edge. Each dword wave-load still fetches
// exactly 2 full 128-B h1 rows. 100000 = 4*25000: grid exact, no guards.
// csr holds pre-shifted byte offsets (1 v_add addressing); tail slots clamp
// to the sentinel zero row (L1-resident). Fused PAN combine + relu + rank-4
// projection -> u; h1 never hits global memory.
__global__ void agg_h_kernel(const unsigned int* __restrict__ lin32,
                             const int* __restrict__ row_start,
                             const int* __restrict__ row_pdeg,
                             const int* __restrict__ csr_src,
                             const float* __restrict__ norm,
                             const float* __restrict__ wpan, const float* __restrict__ w44,
                             const float* __restrict__ bias4, float* __restrict__ u,
                             int n_nodes) {
    int t = threadIdx.x;
    int lane = t & 63;
    int sl = lane & 31;                      // channel dword / edge slot
    int h5 = lane >> 5;                      // half: owns nodes 4q+2*h5 + {0,1}
    int quad = blockIdx.x * 4 + (t >> 6);
    if (blockIdx.x == 0 && t < 4) u[n_nodes * 4 + t] = 0.0f;  // zero row for agg_pq4 pads
    int nX = quad * 4 + h5 * 2;
    int nY = nX + 1;
    int e0X = row_start[nX], pdX = row_pdeg[nX];
    int e0Y = row_start[nY], pdY = row_pdeg[nY];
    int pm = max(pdX, pdY);
    int pmax = max(pm, __shfl_xor(pm, 32));  // wave-uniform chunk bound
    int sentB = n_nodes << 7;                // byte offset of the zero row
    unsigned sl4 = (unsigned)sl * 4;
    const char* base8 = (const char*)lin32;
    float xL0 = 0.f, xH0 = 0.f, xL1 = 0.f, xH1 = 0.f;
    float yL0 = 0.f, yH0 = 0.f, yL1 = 0.f, yH1 = 0.f;
    for (int base = 0; base < pmax; base += 32) {
        int li = base + sl;
        int soX = (li < pdX) ? csr_src[e0X + li] : sentB;
        int soY = (li < pdY) ? csr_src[e0Y + li] : sentB;
        int m = min(32, pmax - base);        // wave-uniform, multiple of 8
#pragma unroll
        for (int i = 0; i < 32; i += 2) {
            if (i < m) {
                int xA0 = __builtin_amdgcn_readlane(soX, i);
                int xB0 = __builtin_amdgcn_readlane(soX, 32 + i);
                int xA1 = __builtin_amdgcn_readlane(soX, i + 1);
                int xB1 = __builtin_amdgcn_readlane(soX, 33 + i);
                int yA0 = __builtin_amdgcn_readlane(soY, i);
                int yB0 = __builtin_amdgcn_readlane(soY, 32 + i);
                int yA1 = __builtin_amdgcn_readlane(soY, i + 1);
                int yB1 = __builtin_amdgcn_readlane(soY, 33 + i);
                int ox0 = h5 ? xB0 : xA0;
                int ox1 = h5 ? xB1 : xA1;
                int oy0 = h5 ? yB0 : yA0;
                int oy1 = h5 ? yB1 : yA1;
                unsigned int wx0 = *(const unsigned int*)(base8 + (unsigned)(ox0 + sl4));
                unsigned int wx1 = *(const unsigned int*)(base8 + (unsigned)(ox1 + sl4));
                unsigned int wy0 = *(const unsigned int*)(base8 + (unsigned)(oy0 + sl4));
                unsigned int wy1 = *(const unsigned int*)(base8 + (unsigned)(oy1 + sl4));
                xL0 += __uint_as_float(wx0 << 16);
                xH0 += __uint_as_float(wx0 & 0xFFFF0000u);
                xL1 += __uint_as_float(wx1 << 16);
                xH1 += __uint_as_float(wx1 & 0xFFFF0000u);
                yL0 += __uint_as_float(wy0 << 16);
                yH0 += __uint_as_float(wy0 & 0xFFFF0000u);
                yL1 += __uint_as_float(wy1 << 16);
                yH1 += __uint_as_float(wy1 & 0xFFFF0000u);
            }
        }
    }
    float aLX = xL0 + xL1, aHX = xH0 + xH1;
    float aLY = yL0 + yL1, aHY = yH0 + yH1;
    // self rows: 32 consecutive dwords per half -> coalesced
    unsigned int wsX = *(const unsigned int*)(base8 + (unsigned)((nX << 7) + sl4));
    unsigned int wsY = *(const unsigned int*)(base8 + (unsigned)((nY << 7) + sl4));
    float nrX = norm[nX], nrY = norm[nY];
    float w0 = wpan[0];
    float w01 = wpan[0] * wpan[1];
    float vLX = fmaxf(nrX * (w0 * __uint_as_float(wsX << 16) + w01 * aLX), 0.0f);
    float vHX = fmaxf(nrX * (w0 * __uint_as_float(wsX & 0xFFFF0000u) + w01 * aHX), 0.0f);
    float vLY = fmaxf(nrY * (w0 * __uint_as_float(wsY << 16) + w01 * aLY), 0.0f);
    float vHY = fmaxf(nrY * (w0 * __uint_as_float(wsY & 0xFFFF0000u) + w01 * aHY), 0.0f);
    int c0 = 2 * sl;
    float4 wv0 = *(const float4*)(w44 + c0 * 4);
    float4 wv1 = *(const float4*)(w44 + (c0 + 1) * 4);
    float pX0 = vLX * wv0.x + vHX * wv1.x;
    float pX1 = vLX * wv0.y + vHX * wv1.y;
    float pX2 = vLX * wv0.z + vHX * wv1.z;
    float pX3 = vLX * wv0.w + vHX * wv1.w;
    float pY0 = vLY * wv0.x + vHY * wv1.x;
    float pY1 = vLY * wv0.y + vHY * wv1.y;
    float pY2 = vLY * wv0.z + vHY * wv1.z;
    float pY3 = vLY * wv0.w + vHY * wv1.w;
    for (int off = 16; off; off >>= 1) {     // reduce within the 32-lane half
        pX0 += __shfl_xor(pX0, off);
        pX1 += __shfl_xor(pX1, off);
        pX2 += __shfl_xor(pX2, off);
        pX3 += __shfl_xor(pX3, off);
        pY0 += __shfl_xor(pY0, off);
        pY1 += __shfl_xor(pY1, off);
        pY2 += __shfl_xor(pY2, off);
        pY3 += __shfl_xor(pY3, off);
    }
    if (sl == 0) {                           // lanes 0/32 write node X
        float4 bb = *(const float4*)bias4;
        *(float4*)(u + nX * 4) =
            make_float4(pX0 + bb.x, pX1 + bb.y, pX2 + bb.z, pX3 + bb.w);
    }
    if (sl == 1) {                           // lanes 1/33 write node Y
        float4 bb = *(const float4*)bias4;
        *(float4*)(u + nY * 4) =
            make_float4(pY0 + bb.x, pY1 + bb.y, pY2 + bb.z, pY3 + bb.w);
    }
}

// Layer-2 aggregate on the rank-4 table (x8-padded rows, branch-free):
// pq[n,j] = norm*(w0*u[n,j] + w01*sum u[src,j]).  csr holds s*128 byte offsets;
// u row start (float index) = s*4 = offset>>5.
__global__ void agg_pq4_kernel(const float* __restrict__ u, const int* __restrict__ row_start,
                               const int* __restrict__ row_pdeg,
                               const int* __restrict__ csr_src,
                               const float* __restrict__ norm,
                               const float* __restrict__ wpan, float* __restrict__ pq,
                               int n_nodes) {
    int t = threadIdx.x;
    int node = blockIdx.x * 64 + (t >> 2);
    int j = t & 3;
    if (node >= n_nodes) return;
    int e0 = row_start[node];
    int pd = row_pdeg[node];
    float acc = 0.0f;
    for (int e = 0; e < pd; e += 8) {
#pragma unroll
        for (int k = 0; k < 8; k++) {
            int so = csr_src[e0 + e + k];
            acc += u[(so >> 5) + j];
        }
    }
    float w0 = wpan[0];
    float w01 = wpan[0] * wpan[1];
    pq[node * 4 + j] = norm[node] * (w0 * u[node * 4 + j] + w01 * acc);
}

__global__ void edge_out_kernel(const int* __restrict__ src, const int* __restrict__ dst,
                                const float* __restrict__ pq, const float* __restrict__ bc,
                                float* __restrict__ out, int n_edges) {
    int e = blockIdx.x * blockDim.x + threadIdx.x;
    if (e >= n_edges) return;
    int r = src[e], c = dst[e];
    float2 p = *(const float2*)(pq + r * 4);
    float2 q = *(const float2*)(pq + c * 4 + 2);
    float2 o = make_float2(p.x + q.x + bc[0], p.y + q.y + bc[1]);
    *(float2*)(out + e * 2) = o;
}

extern "C" void kernel_launch(void* const* d_in, const int* in_sizes, int n_in,
                              void* d_out, int out_size, void* d_ws, size_t ws_size,
                              hipStream_t stream) {
    const float* x      = (const float*)d_in[0];
    const int*   eidx   = (const int*)d_in[1];
    const float* w1_lin = (const float*)d_in[2];
    const float* b1_lin = (const float*)d_in[3];
    const float* w1_pan = (const float*)d_in[4];
    const float* w2_lin = (const float*)d_in[5];
    const float* b2_lin = (const float*)d_in[6];
    const float* w2_pan = (const float*)d_in[7];
    const float* wc     = (const float*)d_in[8];
    const float* bc     = (const float*)d_in[9];
    float* out = (float*)d_out;

    const int* src = eidx;           // edge_index[0]
    const int* dst = eidx + NEDGES;  // edge_index[1]

    // ---- workspace carve-up (all 256B-aligned) ----
    char* ws = (char*)d_ws;
    size_t off = 0;
    auto carve = [&](size_t bytes) {
        char* p = ws + off;
        off = (off + bytes + 255) & ~(size_t)255;
        return p;
    };
    int*   bucket_fill = (int*)carve((size_t)NB * 4);
    int*   row_start = (int*)carve((size_t)NNODES * 4);
    int*   row_pdeg  = (int*)carve((size_t)NNODES * 4);
    unsigned int* staging = (unsigned int*)carve((size_t)NB * CAP * 4);   // 12.8 MB
    int*   csr_src  = (int*)carve(((size_t)NB * CAPE + 256) * 4);         // 12.8 MB + slack
    float* nrm      = (float*)carve((size_t)NNODES * 4);
    unsigned short* bufA = (unsigned short*)carve((size_t)(NNODES + 1) * HIDC * 2);
    float* u        = (float*)carve((size_t)(NNODES + 1) * 4 * 4);
    float* pq       = (float*)carve((size_t)NNODES * 4 * 4);
    float* w44      = (float*)carve((size_t)64 * 4 * 4);
    float* bias4    = (float*)carve((size_t)4 * 4);
    unsigned short* wTh = (unsigned short*)carve((size_t)HIDC * INC * 2); // 16 KB
    unsigned short* wTl = (unsigned short*)carve((size_t)HIDC * INC * 2); // 16 KB
    (void)ws_size; (void)in_sizes; (void)n_in; (void)out_size;

    hipMemsetAsync(bucket_fill, 0, (size_t)NB * 4, stream);

    // kernel 1: prep (wT split + w44/bias4 + sentinel) || fill1 edge binning
    prepfill1_kernel<<<NPREP + NBLK_FILL, 256, 0, stream>>>(
        w1_lin, wTh, wTl, w2_lin, b2_lin, wc, w44, bias4, bufA,
        src, dst, bucket_fill, staging);

    // kernel 2: layer-1 MFMA GEMM (blocks first) || fill2 CSR build (overlapped)
    gemmfill2_kernel<<<NBLK_LIN + NB, 256, 0, stream>>>(
        x, wTh, wTl, b1_lin, bufA,
        bucket_fill, staging, csr_src, row_start, row_pdeg, nrm, NNODES);

    // layer 1 aggregate+relu fused with rank-4 projection -> u (4 nodes/wave)
    agg_h_kernel<<<(NNODES / 16), 256, 0, stream>>>(
        (const unsigned int*)bufA, row_start, row_pdeg, csr_src, nrm, w1_pan, w44, bias4,
        u, NNODES);

    // layer 2 aggregate on the rank-4 table
    agg_pq4_kernel<<<(NNODES + 63) / 64, 256, 0, stream>>>(
        u, row_start, row_pdeg, csr_src, nrm, w2_pan, pq, NNODES);

    // edge head: out[e] = p[src[e]] + q[dst[e]] + bc
    edge_out_kernel<<<NEDGES / 256, 256, 0, stream>>>(src, dst, pq, bc, out, NEDGES);
}

// Round 12
// 222.330 us; speedup vs baseline: 1.0225x; 1.0001x over previous
//
#include <hip/hip_runtime.h>
#include <hip/hip_bf16.h>

#define NNODES 100000
#define NEDGES 1600000
#define INC 128
#define HIDC 64
#define BSHIFT 7                      // 128 nodes per bucket
#define NB ((NNODES + 127) / 128)     // 782 buckets
#define TILE 4096                     // edges per fill1 workgroup (16/thread)
#define HSLOTS 4096                   // LDS hash slots in fill2 (16 KB)
#define CAP 4096                      // staging words per bucket (avg load ~2046)
#define CAPE 4096                     // csr words per bucket (rows padded to x8)
#define NBLK_FILL ((NEDGES + TILE - 1) / TILE)   // 391
#define NBLK_LIN ((NNODES + 63) / 64)            // 1563
#define NPREP 32                      // prep blocks in kernel 1

typedef short bf16x8 __attribute__((ext_vector_type(8)));
typedef float f32x4 __attribute__((ext_vector_type(4)));

__device__ __forceinline__ float bf2f(unsigned short h) {
    return __uint_as_float((unsigned)h << 16);
}
__device__ __forceinline__ unsigned short f2bf(float f) {
    __hip_bfloat16 h = __float2bfloat16(f);
    return *(unsigned short*)&h;
}

// ---- kernel 1: prep (blocks [0,32)) + fill1 binning (blocks [32, 32+391)) ----
__global__ __launch_bounds__(256) void prepfill1_kernel(
        const float* __restrict__ w1, unsigned short* __restrict__ wTh,
        unsigned short* __restrict__ wTl,
        const float* __restrict__ w2_lin, const float* __restrict__ b2,
        const float* __restrict__ wc, float* __restrict__ w44,
        float* __restrict__ bias4, unsigned short* __restrict__ out,
        const int* __restrict__ src, const int* __restrict__ dst,
        int* __restrict__ bucket_fill, unsigned int* __restrict__ staging) {
    __shared__ alignas(16) unsigned char smem[22528];   // fill1: cnt+basepos+svl
    int t = threadIdx.x;
    if (blockIdx.x < NPREP) {
        // ---------------- prep branch ----------------
        int e = blockIdx.x * 256 + t;            // 0..8191 over wT[64][128]
        int c = e >> 7, k = e & 127;
        float v = w1[k * 64 + c];
        unsigned short hi = f2bf(v);
        wTh[e] = hi;
        wTl[e] = f2bf(v - bf2f(hi));
        if (blockIdx.x == 0) {
            if (t < 16)   // zero sentinel row for padded gathers
                *(ushort4*)(out + (size_t)NNODES * 64 + t * 4) = make_ushort4(0, 0, 0, 0);
            int kk = t >> 2, j = t & 3;
            float a = 0.0f;
#pragma unroll 8
            for (int i = 0; i < 64; i++) {
                float w4 = (j < 2) ? wc[i * 2 + j] : wc[(64 + i) * 2 + (j - 2)];
                a += w2_lin[kk * 64 + i] * w4;
            }
            w44[kk * 4 + j] = a;
            if (kk == 0) {
                float bb4 = 0.0f;
                for (int i = 0; i < 64; i++) {
                    float w4 = (j < 2) ? wc[i * 2 + j] : wc[(64 + i) * 2 + (j - 2)];
                    bb4 += b2[i] * w4;
                }
                bias4[j] = bb4;
            }
        }
    } else {
        // ---------------- fill1 branch ----------------
        int* cnt = (int*)smem;
        int* basepos = cnt + NB;
        unsigned int* svl = (unsigned int*)(basepos + NB);   // 4096 words = TILE
        for (int i = t; i < NB; i += 256) cnt[i] = 0;
        int tile0 = (blockIdx.x - NPREP) * TILE;
        // hoist: issue all 32 independent edge loads up-front
        int se[16], de[16];
#pragma unroll
        for (int i = 0; i < 16; i++) {
            int e = tile0 + i * 256 + t;
            if (e < NEDGES) { se[i] = src[e]; de[i] = dst[e]; }
            else            { se[i] = -1;     de[i] = 0; }
        }
        __syncthreads();
        int meta[16];
#pragma unroll
        for (int i = 0; i < 16; i++) {
            meta[i] = -1;
            if (se[i] >= 0) {
                int bkt = de[i] >> BSHIFT;
                int r = atomicAdd(&cnt[bkt], 1);     // < TILE = 4096 (12 bits)
                meta[i] = (bkt << 12) | r;
                svl[i * 256 + t] = ((unsigned)(de[i] & 127) << 17) | (unsigned)se[i];
            }
        }
        __syncthreads();
        for (int i = t; i < NB; i += 256) {
            int c = cnt[i];
            int g = (c > 0) ? atomicAdd(&bucket_fill[i], c) : 0;
            basepos[i] = (i << 12) + g;              // staging region = [i*CAP, ...)
        }
        __syncthreads();
#pragma unroll
        for (int i = 0; i < 16; i++) {
            if (meta[i] >= 0) {
                int bkt = meta[i] >> 12, r = meta[i] & 4095;
                staging[basepos[bkt] + r] = svl[i * 256 + t];
            }
        }
    }
}

// ---- kernel 2: MFMA lin1 GEMM (blocks [0,1563)) + fill2 CSR build (rest) ----
// GEMM is bf16x3 error-compensated: h = xh*wh + xh*wl + xl*wh.
// Hybrid staging (R7-proven): A direct global->reg, B LDS-staged/swizzled.
__global__ __launch_bounds__(256, 5) void gemmfill2_kernel(
        const float* __restrict__ x,
        const unsigned short* __restrict__ wTh, const unsigned short* __restrict__ wTl,
        const float* __restrict__ b, unsigned short* __restrict__ out,
        const int* __restrict__ bucket_fill, const unsigned int* __restrict__ staging,
        int* __restrict__ csr_src, int* __restrict__ row_start,
        int* __restrict__ row_pdeg, float* __restrict__ norm, int n_nodes) {
    __shared__ alignas(16) unsigned char smem[32768];   // union: B 32KB | fill2 26.6KB
    int t = threadIdx.x;
    if (blockIdx.x < NBLK_LIN) {
        // ------- hybrid MFMA GEMM branch: 64 nodes x 64 cols, K=128 -------
        unsigned short* s_bh = (unsigned short*)smem;        // [64][128] swizzled
        unsigned short* s_bl = s_bh + 64 * 128;
        int node0 = blockIdx.x * 64;
        int l = t & 63, wv = t >> 6;
        int mr = l & 15, g = l >> 4;
        int arow = wv * 16 + mr;
        int node = node0 + arow;
        bool vr = (node < NNODES);
        const float* xr = x + (size_t)node * INC;
        float4 vx[8];
#pragma unroll
        for (int ks = 0; ks < 4; ks++) {
            int k0 = ks * 32 + g * 8;
            vx[2 * ks]     = vr ? *(const float4*)(xr + k0)
                                : make_float4(0.f, 0.f, 0.f, 0.f);
            vx[2 * ks + 1] = vr ? *(const float4*)(xr + k0 + 4)
                                : make_float4(0.f, 0.f, 0.f, 0.f);
        }
#pragma unroll
        for (int i = 0; i < 4; i++) {
            int e = i * 256 + t;                     // ushort8 chunk of wT[64][128]
            uint4 vh = *(const uint4*)(wTh + (size_t)e * 8);
            uint4 vl = *(const uint4*)(wTl + (size_t)e * 8);
            int col = e >> 4, k0 = (e & 15) * 8;
            int ke = k0 ^ ((col & 7) << 3);
            *(uint4*)&s_bh[col * 128 + ke] = vh;
            *(uint4*)&s_bl[col * 128 + ke] = vl;
        }
        __syncthreads();
        f32x4 acc[4] = {{0.f, 0.f, 0.f, 0.f}, {0.f, 0.f, 0.f, 0.f},
                        {0.f, 0.f, 0.f, 0.f}, {0.f, 0.f, 0.f, 0.f}};
#pragma unroll
        for (int ks = 0; ks < 4; ks++) {
            int k0 = ks * 32 + g * 8;
            float xv[8] = {vx[2 * ks].x, vx[2 * ks].y, vx[2 * ks].z, vx[2 * ks].w,
                           vx[2 * ks + 1].x, vx[2 * ks + 1].y,
                           vx[2 * ks + 1].z, vx[2 * ks + 1].w};
            bf16x8 ah, al;
#pragma unroll
            for (int j = 0; j < 8; j++) {
                unsigned short h = f2bf(xv[j]);
                ah[j] = (short)h;
                al[j] = (short)f2bf(xv[j] - bf2f(h));
            }
#pragma unroll
            for (int cb = 0; cb < 4; cb++) {
                int col = cb * 16 + mr;
                int ko = k0 ^ ((col & 7) << 3);
                bf16x8 bh = *(const bf16x8*)&s_bh[col * 128 + ko];
                bf16x8 bl = *(const bf16x8*)&s_bl[col * 128 + ko];
                acc[cb] = __builtin_amdgcn_mfma_f32_16x16x32_bf16(ah, bh, acc[cb], 0, 0, 0);
                acc[cb] = __builtin_amdgcn_mfma_f32_16x16x32_bf16(ah, bl, acc[cb], 0, 0, 0);
                acc[cb] = __builtin_amdgcn_mfma_f32_16x16x32_bf16(al, bh, acc[cb], 0, 0, 0);
            }
        }
#pragma unroll
        for (int cb = 0; cb < 4; cb++) {
            int col = cb * 16 + mr;
            float bb = b[col];
#pragma unroll
            for (int r = 0; r < 4; r++) {
                int n2 = node0 + wv * 16 + g * 4 + r;
                if (n2 < NNODES)
                    out[(size_t)n2 * 64 + col] = f2bf(acc[cb][r] + bb);
            }
        }
    } else {
        // ---------------- fill2 branch ----------------
        int* cnt = (int*)smem;                   // 128 ints
        int* dcount = cnt + 128;
        int* off = dcount + 128;
        int* pscan = off + 128;
        unsigned short* rank16 = (unsigned short*)(pscan + 128);   // 8 KB
        unsigned int* ht = (unsigned int*)(rank16 + CAP);          // 16 KB
        int b2k = blockIdx.x - NBLK_LIN;
        int node0 = b2k << BSHIFT;
        int nn = min(128, n_nodes - node0);
        if (t < 128) { cnt[t] = 0; dcount[t] = 0; }
        {
            uint4* h4 = (uint4*)ht;
            uint4 ff = make_uint4(0xFFFFFFFFu, 0xFFFFFFFFu, 0xFFFFFFFFu, 0xFFFFFFFFu);
            for (int i = t; i < HSLOTS / 4; i += 256) h4[i] = ff;
        }
        __syncthreads();
        int start = b2k << 12;
        int total = bucket_fill[b2k];
        // phase A: count + rank + dedup
        for (int li = t; li < total; li += 256) {
            unsigned int w = staging[start + li];
            int s = (int)(w & 0x1FFFFu);
            int dl = (int)(w >> 17);
            int r = atomicAdd(&cnt[dl], 1);
            rank16[li] = (unsigned short)r;
            if (s != node0 + dl) {  // self-loops merge with the I-diagonal
                unsigned int slot = ((w * 2654435761u) >> 13) & (HSLOTS - 1);
                while (true) {
                    unsigned int prev = atomicCAS(&ht[slot], 0xFFFFFFFFu, w);
                    if (prev == 0xFFFFFFFFu) { atomicAdd(&dcount[dl], 1); break; }
                    if (prev == w) break;
                    slot = (slot + 1) & (HSLOTS - 1);
                }
            }
        }
        __syncthreads();
        int cv = 0, pv = 0;
        if (t < 128) {
            cv = cnt[t];
            pv = (cv + 7) & ~7;
            pscan[t] = pv;
        }
        __syncthreads();
        for (int o = 1; o < 128; o <<= 1) {
            int xx = (t >= o && t < 128) ? pscan[t - o] : 0;
            __syncthreads();
            if (t < 128) pscan[t] += xx;
            __syncthreads();
        }
        if (t < 128) off[t] = b2k * CAPE + pscan[t] - pv;
        __syncthreads();
        if (t < nn) {
            row_start[node0 + t] = off[t];
            row_pdeg[node0 + t] = pv;
            norm[node0 + t] = 1.0f / (1.0f + (float)dcount[t]);
        }
        if (t < 128)
            for (int k = cv; k < pv; k++) csr_src[off[t] + k] = n_nodes << 7;
        // phase B: scatter csr (byte offsets: s*128)
        for (int li = t; li < total; li += 256) {
            unsigned int w = staging[start + li];
            int s = (int)(w & 0x1FFFFu);
            int dl = (int)(w >> 17);
            csr_src[off[dl] + (int)rank16[li]] = s << 7;
        }
    }
}

// Four nodes per wave (R5-proven): lanes 0-31 own nodes {4q,4q+1}, lanes
// 32-63 own {4q+2,4q+3}; two edge streams per half, MLP=4 dword gathers.
__global__ void agg_h_kernel(const unsigned int* __restrict__ lin32,
                             const int* __restrict__ row_start,
                             const int* __restrict__ row_pdeg,
                             const int* __restrict__ csr_src,
                             const float* __restrict__ norm,
                             const float* __restrict__ wpan, const float* __restrict__ w44,
                             const float* __restrict__ bias4, float* __restrict__ u,
                             int n_nodes) {
    int t = threadIdx.x;
    int lane = t & 63;
    int sl = lane & 31;                      // channel dword / edge slot
    int h5 = lane >> 5;                      // half: owns nodes 4q+2*h5 + {0,1}
    int quad = blockIdx.x * 4 + (t >> 6);
    if (blockIdx.x == 0 && t < 4) u[n_nodes * 4 + t] = 0.0f;  // zero row for agg_pq4 pads
    int nX = quad * 4 + h5 * 2;
    int nY = nX + 1;
    int e0X = row_start[nX], pdX = row_pdeg[nX];
    int e0Y = row_start[nY], pdY = row_pdeg[nY];
    int pm = max(pdX, pdY);
    int pmax = max(pm, __shfl_xor(pm, 32));  // wave-uniform chunk bound
    int sentB = n_nodes << 7;                // byte offset of the zero row
    unsigned sl4 = (unsigned)sl * 4;
    const char* base8 = (const char*)lin32;
    float xL0 = 0.f, xH0 = 0.f, xL1 = 0.f, xH1 = 0.f;
    float yL0 = 0.f, yH0 = 0.f, yL1 = 0.f, yH1 = 0.f;
    for (int base = 0; base < pmax; base += 32) {
        int li = base + sl;
        int soX = (li < pdX) ? csr_src[e0X + li] : sentB;
        int soY = (li < pdY) ? csr_src[e0Y + li] : sentB;
        int m = min(32, pmax - base);        // wave-uniform, multiple of 8
#pragma unroll
        for (int i = 0; i < 32; i += 2) {
            if (i < m) {
                int xA0 = __builtin_amdgcn_readlane(soX, i);
                int xB0 = __builtin_amdgcn_readlane(soX, 32 + i);
                int xA1 = __builtin_amdgcn_readlane(soX, i + 1);
                int xB1 = __builtin_amdgcn_readlane(soX, 33 + i);
                int yA0 = __builtin_amdgcn_readlane(soY, i);
                int yB0 = __builtin_amdgcn_readlane(soY, 32 + i);
                int yA1 = __builtin_amdgcn_readlane(soY, i + 1);
                int yB1 = __builtin_amdgcn_readlane(soY, 33 + i);
                int ox0 = h5 ? xB0 : xA0;
                int ox1 = h5 ? xB1 : xA1;
                int oy0 = h5 ? yB0 : yA0;
                int oy1 = h5 ? yB1 : yA1;
                unsigned int wx0 = *(const unsigned int*)(base8 + (unsigned)(ox0 + sl4));
                unsigned int wx1 = *(const unsigned int*)(base8 + (unsigned)(ox1 + sl4));
                unsigned int wy0 = *(const unsigned int*)(base8 + (unsigned)(oy0 + sl4));
                unsigned int wy1 = *(const unsigned int*)(base8 + (unsigned)(oy1 + sl4));
                xL0 += __uint_as_float(wx0 << 16);
                xH0 += __uint_as_float(wx0 & 0xFFFF0000u);
                xL1 += __uint_as_float(wx1 << 16);
                xH1 += __uint_as_float(wx1 & 0xFFFF0000u);
                yL0 += __uint_as_float(wy0 << 16);
                yH0 += __uint_as_float(wy0 & 0xFFFF0000u);
                yL1 += __uint_as_float(wy1 << 16);
                yH1 += __uint_as_float(wy1 & 0xFFFF0000u);
            }
        }
    }
    float aLX = xL0 + xL1, aHX = xH0 + xH1;
    float aLY = yL0 + yL1, aHY = yH0 + yH1;
    unsigned int wsX = *(const unsigned int*)(base8 + (unsigned)((nX << 7) + sl4));
    unsigned int wsY = *(const unsigned int*)(base8 + (unsigned)((nY << 7) + sl4));
    float nrX = norm[nX], nrY = norm[nY];
    float w0 = wpan[0];
    float w01 = wpan[0] * wpan[1];
    float vLX = fmaxf(nrX * (w0 * __uint_as_float(wsX << 16) + w01 * aLX), 0.0f);
    float vHX = fmaxf(nrX * (w0 * __uint_as_float(wsX & 0xFFFF0000u) + w01 * aHX), 0.0f);
    float vLY = fmaxf(nrY * (w0 * __uint_as_float(wsY << 16) + w01 * aLY), 0.0f);
    float vHY = fmaxf(nrY * (w0 * __uint_as_float(wsY & 0xFFFF0000u) + w01 * aHY), 0.0f);
    int c0 = 2 * sl;
    float4 wv0 = *(const float4*)(w44 + c0 * 4);
    float4 wv1 = *(const float4*)(w44 + (c0 + 1) * 4);
    float pX0 = vLX * wv0.x + vHX * wv1.x;
    float pX1 = vLX * wv0.y + vHX * wv1.y;
    float pX2 = vLX * wv0.z + vHX * wv1.z;
    float pX3 = vLX * wv0.w + vHX * wv1.w;
    float pY0 = vLY * wv0.x + vHY * wv1.x;
    float pY1 = vLY * wv0.y + vHY * wv1.y;
    float pY2 = vLY * wv0.z + vHY * wv1.z;
    float pY3 = vLY * wv0.w + vHY * wv1.w;
    for (int off = 16; off; off >>= 1) {     // reduce within the 32-lane half
        pX0 += __shfl_xor(pX0, off);
        pX1 += __shfl_xor(pX1, off);
        pX2 += __shfl_xor(pX2, off);
        pX3 += __shfl_xor(pX3, off);
        pY0 += __shfl_xor(pY0, off);
        pY1 += __shfl_xor(pY1, off);
        pY2 += __shfl_xor(pY2, off);
        pY3 += __shfl_xor(pY3, off);
    }
    if (sl == 0) {                           // lanes 0/32 write node X
        float4 bb = *(const float4*)bias4;
        *(float4*)(u + nX * 4) =
            make_float4(pX0 + bb.x, pX1 + bb.y, pX2 + bb.z, pX3 + bb.w);
    }
    if (sl == 1) {                           // lanes 1/33 write node Y
        float4 bb = *(const float4*)bias4;
        *(float4*)(u + nY * 4) =
            make_float4(pY0 + bb.x, pY1 + bb.y, pY2 + bb.z, pY3 + bb.w);
    }
}

// Layer-2 aggregate, R11 re-laned: 4 lanes per node, ONE EDGE PER LANE with
// a single float4 gather per edge (was 4 scattered dwords + 4x-duplicated csr
// reads = ~15M requests; now ~2.8M). Lane l owns edges l, l+4, ...; unroll x2
// (pd % 8 == 0 -> exact) keeps 4 gathers in flight. Partial float4 sums are
// combined with 2 shfl_xor steps; lane 0 reads u[node] as float4 and writes
// the pq row as float4. csr holds s*128 byte offsets; u row byte offset =
// s*16 = so>>3. Sentinel pads point at the zeroed row -> safe.
__global__ void agg_pq4_kernel(const float* __restrict__ u, const int* __restrict__ row_start,
                               const int* __restrict__ row_pdeg,
                               const int* __restrict__ csr_src,
                               const float* __restrict__ norm,
                               const float* __restrict__ wpan, float* __restrict__ pq,
                               int n_nodes) {
    int t = threadIdx.x;
    int node = blockIdx.x * 64 + (t >> 2);
    int l = t & 3;
    if (node >= n_nodes) return;
    int e0 = row_start[node];
    int pd = row_pdeg[node];                 // multiple of 8
    const char* ub = (const char*)u;
    float4 acc = make_float4(0.f, 0.f, 0.f, 0.f);
    for (int e = l; e < pd; e += 8) {        // lane l: edges l, l+4, l+8, ...
        int so0 = csr_src[e0 + e];
        int so1 = csr_src[e0 + e + 4];
        float4 v0 = *(const float4*)(ub + ((unsigned)so0 >> 3));
        float4 v1 = *(const float4*)(ub + ((unsigned)so1 >> 3));
        acc.x += v0.x + v1.x;
        acc.y += v0.y + v1.y;
        acc.z += v0.z + v1.z;
        acc.w += v0.w + v1.w;
    }
    // combine the 4 per-lane partials (lanes l=0..3 of this node)
    for (int off = 1; off < 4; off <<= 1) {
        acc.x += __shfl_xor(acc.x, off);
        acc.y += __shfl_xor(acc.y, off);
        acc.z += __shfl_xor(acc.z, off);
        acc.w += __shfl_xor(acc.w, off);
    }
    if (l == 0) {
        float4 un = *(const float4*)(u + (size_t)node * 4);
        float nr = norm[node];
        float w0 = wpan[0];
        float w01 = wpan[0] * wpan[1];
        float4 o;
        o.x = nr * (w0 * un.x + w01 * acc.x);
        o.y = nr * (w0 * un.y + w01 * acc.y);
        o.z = nr * (w0 * un.z + w01 * acc.z);
        o.w = nr * (w0 * un.w + w01 * acc.w);
        *(float4*)(pq + (size_t)node * 4) = o;
    }
}

__global__ void edge_out_kernel(const int* __restrict__ src, const int* __restrict__ dst,
                                const float* __restrict__ pq, const float* __restrict__ bc,
                                float* __restrict__ out, int n_edges) {
    int e = blockIdx.x * blockDim.x + threadIdx.x;
    if (e >= n_edges) return;
    int r = src[e], c = dst[e];
    float2 p = *(const float2*)(pq + r * 4);
    float2 q = *(const float2*)(pq + c * 4 + 2);
    float2 o = make_float2(p.x + q.x + bc[0], p.y + q.y + bc[1]);
    *(float2*)(out + e * 2) = o;
}

extern "C" void kernel_launch(void* const* d_in, const int* in_sizes, int n_in,
                              void* d_out, int out_size, void* d_ws, size_t ws_size,
                              hipStream_t stream) {
    const float* x      = (const float*)d_in[0];
    const int*   eidx   = (const int*)d_in[1];
    const float* w1_lin = (const float*)d_in[2];
    const float* b1_lin = (const float*)d_in[3];
    const float* w1_pan = (const float*)d_in[4];
    const float* w2_lin = (const float*)d_in[5];
    const float* b2_lin = (const float*)d_in[6];
    const float* w2_pan = (const float*)d_in[7];
    const float* wc     = (const float*)d_in[8];
    const float* bc     = (const float*)d_in[9];
    float* out = (float*)d_out;

    const int* src = eidx;           // edge_index[0]
    const int* dst = eidx + NEDGES;  // edge_index[1]

    // ---- workspace carve-up (all 256B-aligned) ----
    char* ws = (char*)d_ws;
    size_t off = 0;
    auto carve = [&](size_t bytes) {
        char* p = ws + off;
        off = (off + bytes + 255) & ~(size_t)255;
        return p;
    };
    int*   bucket_fill = (int*)carve((size_t)NB * 4);
    int*   row_start = (int*)carve((size_t)NNODES * 4);
    int*   row_pdeg  = (int*)carve((size_t)NNODES * 4);
    unsigned int* staging = (unsigned int*)carve((size_t)NB * CAP * 4);   // 12.8 MB
    int*   csr_src  = (int*)carve(((size_t)NB * CAPE + 256) * 4);         // 12.8 MB + slack
    float* nrm      = (float*)carve((size_t)NNODES * 4);
    unsigned short* bufA = (unsigned short*)carve((size_t)(NNODES + 1) * HIDC * 2);
    float* u        = (float*)carve((size_t)(NNODES + 1) * 4 * 4);
    float* pq       = (float*)carve((size_t)NNODES * 4 * 4);
    float* w44      = (float*)carve((size_t)64 * 4 * 4);
    float* bias4    = (float*)carve((size_t)4 * 4);
    unsigned short* wTh = (unsigned short*)carve((size_t)HIDC * INC * 2); // 16 KB
    unsigned short* wTl = (unsigned short*)carve((size_t)HIDC * INC * 2); // 16 KB
    (void)ws_size; (void)in_sizes; (void)n_in; (void)out_size;

    hipMemsetAsync(bucket_fill, 0, (size_t)NB * 4, stream);

    // kernel 1: prep (wT split + w44/bias4 + sentinel) || fill1 edge binning
    prepfill1_kernel<<<NPREP + NBLK_FILL, 256, 0, stream>>>(
        w1_lin, wTh, wTl, w2_lin, b2_lin, wc, w44, bias4, bufA,
        src, dst, bucket_fill, staging);

    // kernel 2: layer-1 MFMA GEMM (blocks first) || fill2 CSR build (overlapped)
    gemmfill2_kernel<<<NBLK_LIN + NB, 256, 0, stream>>>(
        x, wTh, wTl, b1_lin, bufA,
        bucket_fill, staging, csr_src, row_start, row_pdeg, nrm, NNODES);

    // layer 1 aggregate+relu fused with rank-4 projection -> u (4 nodes/wave)
    agg_h_kernel<<<(NNODES / 16), 256, 0, stream>>>(
        (const unsigned int*)bufA, row_start, row_pdeg, csr_src, nrm, w1_pan, w44, bias4,
        u, NNODES);

    // layer 2 aggregate on the rank-4 table (1 edge/lane, float4 gathers)
    agg_pq4_kernel<<<(NNODES + 63) / 64, 256, 0, stream>>>(
        u, row_start, row_pdeg, csr_src, nrm, w2_pan, pq, NNODES);

    // edge head: out[e] = p[src[e]] + q[dst[e]] + bc
    edge_out_kernel<<<NEDGES / 256, 256, 0, stream>>>(src, dst, pq, bc, out, NEDGES);
}